// Round 1
// baseline (492.231 us; speedup 1.0000x reference)
//
#include <hip/hip_runtime.h>

typedef __attribute__((ext_vector_type(8))) short s8v;
typedef __attribute__((ext_vector_type(4))) float f4v;

#define PAD1 88
#define KP 264
#define QP 260

__device__ __forceinline__ unsigned short f2bf(float f) {
  unsigned u = __float_as_uint(f);
  u += 0x7fffu + ((u >> 16) & 1u);
  return (unsigned short)(u >> 16);
}
__device__ __forceinline__ float bf2f(unsigned short h) {
  return __uint_as_float(((unsigned)h) << 16);
}

// ---------------- prep: W_in'=gamma*W_in split hi/lo transposed, W_out^T bf16,
//                  u=colsum(gamma*W_in), v=beta@W_in, key_norms, d0 ----------------
__global__ void k_prep(const float* __restrict__ W_in, const float* __restrict__ lnis,
                       const float* __restrict__ lnib, const float* __restrict__ W_out,
                       const float* __restrict__ skeys, const float* __restrict__ smem0,
                       const float* __restrict__ wgate,
                       unsigned short* __restrict__ wth, unsigned short* __restrict__ wtl,
                       unsigned short* __restrict__ wot, float* __restrict__ keyn,
                       float* __restrict__ d0, float* __restrict__ uvec, float* __restrict__ vvec)
{
  __shared__ float pr[4];
  const int bid = blockIdx.x, tid = threadIdx.x;
  if (bid < 1024) {
    int idx = bid * 256 + tid;           // wt layout [n=256][k=1024]
    int n = idx >> 10, k = idx & 1023;
    float val = lnis[k] * W_in[k * 256 + n];
    unsigned short h = f2bf(val);
    wth[idx] = h;
    wtl[idx] = f2bf(val - bf2f(h));
  } else if (bid < 2048) {
    int idx = (bid - 1024) * 256 + tid;  // wot layout [n=1024][k=256]
    int n = idx >> 8, k = idx & 255;
    wot[idx] = f2bf(W_out[k * 1024 + n]);
  } else if (bid == 2048) {
    float su = 0.f, sv = 0.f;
    for (int i = 0; i < 1024; ++i) {
      float wv_ = W_in[i * 256 + tid];
      su += lnis[i] * wv_;
      sv += lnib[i] * wv_;
    }
    uvec[tid] = su; vvec[tid] = sv;
  } else {
    int n = bid - 2049;
    float sk = skeys[n * 256 + tid];
    float sq = sk * sk;
    #pragma unroll
    for (int m = 32; m; m >>= 1) sq += __shfl_xor(sq, m);
    if ((tid & 63) == 0) pr[tid >> 6] = sq;
    __syncthreads();
    float tot = pr[0] + pr[1] + pr[2] + pr[3];
    keyn[n * 256 + tid] = sk * (1.0f / fmaxf(sqrtf(tot), 1e-12f));
    float pd = smem0[n * 256 + tid] * wgate[tid];
    #pragma unroll
    for (int m = 32; m; m >>= 1) pd += __shfl_xor(pd, m);
    __syncthreads();
    if ((tid & 63) == 0) pr[tid >> 6] = pd;
    __syncthreads();
    if (tid == 0) d0[n] = pr[0] + pr[1] + pr[2] + pr[3];
  }
}

// ---------------- per-row LN stats of x ----------------
__global__ void k_stats(const float* __restrict__ x, float* __restrict__ mrow, float* __restrict__ rrow)
{
  const int r = blockIdx.x * 8 + (threadIdx.x >> 5);
  const int j = threadIdx.x & 31;
  const float* p = x + (size_t)r * 1024 + j * 32;
  float s = 0.f, ss = 0.f;
  #pragma unroll
  for (int i = 0; i < 32; i += 4) {
    f4v v = *(const f4v*)(p + i);
    s  += v[0] + v[1] + v[2] + v[3];
    ss += v[0]*v[0] + v[1]*v[1] + v[2]*v[2] + v[3]*v[3];
  }
  #pragma unroll
  for (int m = 16; m; m >>= 1) { s += __shfl_xor(s, m); ss += __shfl_xor(ss, m); }
  if (j == 0) {
    float mean = s * (1.0f / 1024.0f);
    mrow[r] = mean;
    rrow[r] = rsqrtf(ss * (1.0f / 1024.0f) - mean * mean + 1e-5f);
  }
}

// ---------------- GEMM1: q = rstd*(x @ W') - rstd*m*u + v, split-bf16 (3 MFMA passes) ----------------
__global__ __launch_bounds__(512, 2) void k_gemm1(const float* __restrict__ x,
    const unsigned short* __restrict__ wth, const unsigned short* __restrict__ wtl,
    const float* __restrict__ mrow, const float* __restrict__ rrow,
    const float* __restrict__ uvec, const float* __restrict__ vvec,
    float* __restrict__ q)
{
  __shared__ unsigned short Ah[128 * PAD1], Al[128 * PAD1];
  __shared__ unsigned short Bh[256 * PAD1], Bl[256 * PAD1];
  __shared__ float uls[256], vls[256];
  const int tid = threadIdx.x;
  const int w = tid >> 6, lane = tid & 63;
  const int wm = w >> 2, wn = w & 3;
  const int row0 = blockIdx.x * 128;
  if (tid < 256) { uls[tid] = uvec[tid]; vls[tid] = vvec[tid]; }
  f4v zz = {0.f, 0.f, 0.f, 0.f};
  f4v acc[4][4];
  #pragma unroll
  for (int i = 0; i < 4; ++i)
    #pragma unroll
    for (int j = 0; j < 4; ++j) acc[i][j] = zz;
  const int rowA = tid >> 2, kqA = (tid & 3) * 16;
  const int colB = tid >> 1, khB = (tid & 1) * 32;
  for (int kt = 0; kt < 16; ++kt) {
    const int k0 = kt * 64;
    {
      const float* src = x + (size_t)(row0 + rowA) * 1024 + k0 + kqA;
      float vv[16];
      #pragma unroll
      for (int i = 0; i < 4; ++i) *(f4v*)(vv + 4 * i) = *(const f4v*)(src + 4 * i);
      unsigned short hh[16], ll[16];
      #pragma unroll
      for (int i = 0; i < 16; ++i) {
        unsigned short hsh = f2bf(vv[i]);
        hh[i] = hsh;
        ll[i] = f2bf(vv[i] - bf2f(hsh));
      }
      unsigned short* dh = &Ah[rowA * PAD1 + kqA];
      unsigned short* dl = &Al[rowA * PAD1 + kqA];
      *(s8v*)dh = *(const s8v*)hh; *(s8v*)(dh + 8) = *(const s8v*)(hh + 8);
      *(s8v*)dl = *(const s8v*)ll; *(s8v*)(dl + 8) = *(const s8v*)(ll + 8);
      const unsigned short* sh = wth + (size_t)colB * 1024 + k0 + khB;
      const unsigned short* sl = wtl + (size_t)colB * 1024 + k0 + khB;
      unsigned short* dbh = &Bh[colB * PAD1 + khB];
      unsigned short* dbl = &Bl[colB * PAD1 + khB];
      #pragma unroll
      for (int i = 0; i < 4; ++i) {
        *(s8v*)(dbh + 8 * i) = *(const s8v*)(sh + 8 * i);
        *(s8v*)(dbl + 8 * i) = *(const s8v*)(sl + 8 * i);
      }
    }
    __syncthreads();
    #pragma unroll
    for (int kk = 0; kk < 64; kk += 32) {
      const int kb = kk + (lane >> 4) * 8;
      s8v ah[4], al[4], bh[4], bl[4];
      #pragma unroll
      for (int mi = 0; mi < 4; ++mi) {
        const int rr = (wm * 64 + mi * 16 + (lane & 15)) * PAD1 + kb;
        ah[mi] = *(const s8v*)&Ah[rr];
        al[mi] = *(const s8v*)&Al[rr];
      }
      #pragma unroll
      for (int ni = 0; ni < 4; ++ni) {
        const int ccv = (wn * 64 + ni * 16 + (lane & 15)) * PAD1 + kb;
        bh[ni] = *(const s8v*)&Bh[ccv];
        bl[ni] = *(const s8v*)&Bl[ccv];
      }
      #pragma unroll
      for (int mi = 0; mi < 4; ++mi)
        #pragma unroll
        for (int ni = 0; ni < 4; ++ni) {
          acc[mi][ni] = __builtin_amdgcn_mfma_f32_16x16x32_bf16(ah[mi], bh[ni], acc[mi][ni], 0, 0, 0);
          acc[mi][ni] = __builtin_amdgcn_mfma_f32_16x16x32_bf16(ah[mi], bl[ni], acc[mi][ni], 0, 0, 0);
          acc[mi][ni] = __builtin_amdgcn_mfma_f32_16x16x32_bf16(al[mi], bh[ni], acc[mi][ni], 0, 0, 0);
        }
    }
    __syncthreads();
  }
  #pragma unroll
  for (int mi = 0; mi < 4; ++mi)
    #pragma unroll
    for (int j = 0; j < 4; ++j) {
      const int r = row0 + wm * 64 + mi * 16 + (lane >> 4) * 4 + j;
      const float mv = mrow[r], rv = rrow[r];
      #pragma unroll
      for (int ni = 0; ni < 4; ++ni) {
        const int cidx = wn * 64 + ni * 16 + (lane & 15);
        q[(size_t)r * 256 + cidx] = rv * acc[mi][ni][j] - rv * mv * uls[cidx] + vls[cidx];
      }
    }
}

// ---------------- attention: per wave = (chunk, head). softmax over 64 slots, read (bf16) + chunk summary ----------------
__global__ __launch_bounds__(512, 2) void k_attn(const float* __restrict__ q,
    const float* __restrict__ smem0, unsigned short* __restrict__ readb,
    float* __restrict__ summ)
{
  __shared__ float ks[64 * KP];
  __shared__ float qs[2][16 * QP];
  __shared__ float as_[8][64 * 20];
  const int tid = threadIdx.x;
  const int w = tid >> 6, lane = tid & 63;
  const int cl = w >> 2, h = w & 3;
  const int g = blockIdx.x * 2 + cl;
  const int bb = g >> 8, cc = g & 255;
  const int rowbase = bb * 4096 + cc * 16;

  #pragma unroll
  for (int i = 0; i < 32; ++i) {
    int idx = i * 512 + tid;
    ks[(idx >> 8) * KP + (idx & 255)] = smem0[idx];
  }
  {
    const int c2 = tid >> 8;
    const int rr = (tid >> 4) & 15;
    const int dq = (tid & 15) * 16;
    const int g2 = blockIdx.x * 2 + c2;
    const float* src = q + (size_t)((g2 >> 8) * 4096 + (g2 & 255) * 16 + rr) * 256 + dq;
    float* dst = &qs[c2][rr * QP + dq];
    #pragma unroll
    for (int i = 0; i < 4; ++i) *(f4v*)(dst + 4 * i) = *(const f4v*)(src + 4 * i);
  }
  __syncthreads();

  float S[16];
  #pragma unroll
  for (int t = 0; t < 16; ++t) S[t] = 0.f;
  const float* qsl = qs[cl];
  const int hb = h * 64;
  for (int c4 = 0; c4 < 16; ++c4) {
    f4v kv = *(const f4v*)&ks[lane * KP + hb + c4 * 4];
    #pragma unroll
    for (int t = 0; t < 16; ++t) {
      f4v qv = *(const f4v*)&qsl[t * QP + hb + c4 * 4];
      S[t] += qv[0] * kv[0] + qv[1] * kv[1] + qv[2] * kv[2] + qv[3] * kv[3];
    }
  }
  float rsum[16];
  #pragma unroll
  for (int t = 0; t < 16; ++t) {
    float sc = S[t] * 0.125f;
    float mx = sc;
    #pragma unroll
    for (int m = 32; m; m >>= 1) mx = fmaxf(mx, __shfl_xor(mx, m));
    float p = __expf(sc - mx);
    float sm = p;
    #pragma unroll
    for (int m = 32; m; m >>= 1) sm += __shfl_xor(sm, m);
    as_[w][lane * 20 + t] = p;
    rsum[t] = 1.0f / sm;
  }
  float r[16];
  #pragma unroll
  for (int t = 0; t < 16; ++t) r[t] = 0.f;
  for (int n = 0; n < 64; ++n) {
    float kv = ks[n * KP + hb + lane];
    const float* ap = &as_[w][n * 20];
    #pragma unroll
    for (int t4 = 0; t4 < 4; ++t4) {
      f4v av = *(const f4v*)(ap + t4 * 4);
      r[t4 * 4 + 0] += av[0] * kv; r[t4 * 4 + 1] += av[1] * kv;
      r[t4 * 4 + 2] += av[2] * kv; r[t4 * 4 + 3] += av[3] * kv;
    }
  }
  float sp = 0.f;
  #pragma unroll
  for (int t = 0; t < 16; ++t) {
    float rv = r[t] * rsum[t];
    sp += rv;
    readb[(size_t)(rowbase + t) * 256 + hb + lane] = f2bf(rv);
  }
  summ[(size_t)g * 256 + hb + lane] = sp * (1.0f / 16.0f);
}

// ---------------- per-chunk: match -> top3, wv = summary@W_write, wg2 = wv.Wg2, dwv = wv.Wg1 ----------------
__global__ void k_match(const float* __restrict__ summ, const float* __restrict__ keyn,
                        const float* __restrict__ Wwr, const float* __restrict__ wgate,
                        int* __restrict__ top3, float* __restrict__ wv,
                        float* __restrict__ wg2, float* __restrict__ dwv)
{
  __shared__ float sm[4][256];
  __shared__ float nrm_inv[4];
  __shared__ float mtch[4][64];
  __shared__ float redA[4][4], redB[4][4];
  const int tid = threadIdx.x, lane = tid & 63, w = tid >> 6;
  const int gbase = blockIdx.x * 4;
  #pragma unroll
  for (int gi = 0; gi < 4; ++gi) sm[gi][tid] = summ[(size_t)(gbase + gi) * 256 + tid];
  __syncthreads();
  {
    float ss = 0.f;
    #pragma unroll
    for (int i = 0; i < 4; ++i) { float vv_ = sm[w][lane + i * 64]; ss += vv_ * vv_; }
    #pragma unroll
    for (int m = 32; m; m >>= 1) ss += __shfl_xor(ss, m);
    if (lane == 0) nrm_inv[w] = 1.0f / fmaxf(sqrtf(ss), 1e-12f);
  }
  __syncthreads();
  {
    const int n = tid >> 2, qq = tid & 3;
    float mac[4] = {0.f, 0.f, 0.f, 0.f};
    const float* kp = keyn + n * 256 + qq * 64;
    for (int d = 0; d < 64; ++d) {
      float kv = kp[d];
      int dd = qq * 64 + d;
      mac[0] += sm[0][dd] * kv; mac[1] += sm[1][dd] * kv;
      mac[2] += sm[2][dd] * kv; mac[3] += sm[3][dd] * kv;
    }
    #pragma unroll
    for (int gi = 0; gi < 4; ++gi) {
      float v2_ = mac[gi];
      v2_ += __shfl_xor(v2_, 1);
      v2_ += __shfl_xor(v2_, 2);
      if (qq == 0) mtch[gi][n] = v2_ * nrm_inv[gi];
    }
  }
  __syncthreads();
  {
    float vorig = mtch[w][lane];
    #pragma unroll
    for (int it = 0; it < 3; ++it) {
      float rv = vorig; int ri = lane;
      #pragma unroll
      for (int m = 32; m; m >>= 1) {
        float ov = __shfl_xor(rv, m); int oi = __shfl_xor(ri, m);
        if (ov > rv || (ov == rv && oi < ri)) { rv = ov; ri = oi; }
      }
      if (lane == 0) top3[(gbase + w) * 4 + it] = ri;
      if (lane == ri) vorig = -3.0e38f;
    }
  }
  float wva[4] = {0.f, 0.f, 0.f, 0.f};
  for (int d = 0; d < 256; ++d) {
    float ww = Wwr[(size_t)d * 256 + tid];
    wva[0] += sm[0][d] * ww; wva[1] += sm[1][d] * ww;
    wva[2] += sm[2][d] * ww; wva[3] += sm[3][d] * ww;
  }
  const float g1 = wgate[tid], g2 = wgate[256 + tid];
  #pragma unroll
  for (int gi = 0; gi < 4; ++gi) {
    wv[(size_t)(gbase + gi) * 256 + tid] = wva[gi];
    float p2 = wva[gi] * g2, p1 = wva[gi] * g1;
    #pragma unroll
    for (int m = 32; m; m >>= 1) { p2 += __shfl_xor(p2, m); p1 += __shfl_xor(p1, m); }
    if (lane == 0) { redA[gi][w] = p2; redB[gi][w] = p1; }
  }
  __syncthreads();
  if (tid < 4) {
    wg2[gbase + tid] = redA[tid][0] + redA[tid][1] + redA[tid][2] + redA[tid][3];
    dwv[gbase + tid] = redB[tid][0] + redB[tid][1] + redB[tid][2] + redB[tid][3];
  }
}

// ---------------- scan (scalar gate chain) + parallel slot replay + LN -> new_slots ----------------
__global__ __launch_bounds__(1024, 4) void k_scan(const float* __restrict__ d0,
    const int* __restrict__ top3, const float* __restrict__ wg2, const float* __restrict__ dwv,
    const float* __restrict__ bgate, const float* __restrict__ wv,
    const float* __restrict__ smem0, const float* __restrict__ lnss,
    const float* __restrict__ lnsb, float* __restrict__ outns)
{
  __shared__ float gls[256];
  __shared__ int ils[1024];
  __shared__ float wg2s[256], dwvs[256];
  const int bb = blockIdx.x, tid = threadIdx.x;
  ils[tid] = top3[bb * 1024 + tid];
  if (tid < 256) { wg2s[tid] = wg2[bb * 256 + tid]; dwvs[tid] = dwv[bb * 256 + tid]; }
  __syncthreads();
  if (tid < 64) {
    float dn = d0[tid];
    const float bg = bgate[0];
    for (int c = 0; c < 256; ++c) {
      int i0 = ils[c * 4], i1 = ils[c * 4 + 1], i2 = ils[c * 4 + 2];
      float s3 = __shfl(dn, i0) + __shfl(dn, i1) + __shfl(dn, i2);
      float z = s3 * (1.0f / 3.0f) + wg2s[c] + bg;
      float gv = 1.0f / (1.0f + __expf(-z));
      if (tid == 0) gls[c] = gv;
      if (tid == i0 || tid == i1 || tid == i2) dn = (1.0f - gv) * dn + gv * dwvs[c];
    }
  }
  __syncthreads();
  const int n = tid >> 4, dq = tid & 15;
  float v[16];
  {
    const float* p = smem0 + n * 256 + dq * 16;
    #pragma unroll
    for (int i = 0; i < 16; i += 4) *(f4v*)(v + i) = *(const f4v*)(p + i);
  }
  for (int c = 0; c < 256; ++c) {
    int i0 = ils[c * 4], i1 = ils[c * 4 + 1], i2 = ils[c * 4 + 2];
    if (n == i0 || n == i1 || n == i2) {
      float gv = gls[c];
      const float* wvp = wv + (size_t)(bb * 256 + c) * 256 + dq * 16;
      #pragma unroll
      for (int i4 = 0; i4 < 4; ++i4) {
        f4v wq = *(const f4v*)(wvp + i4 * 4);
        v[i4 * 4 + 0] = (1.0f - gv) * v[i4 * 4 + 0] + gv * wq[0];
        v[i4 * 4 + 1] = (1.0f - gv) * v[i4 * 4 + 1] + gv * wq[1];
        v[i4 * 4 + 2] = (1.0f - gv) * v[i4 * 4 + 2] + gv * wq[2];
        v[i4 * 4 + 3] = (1.0f - gv) * v[i4 * 4 + 3] + gv * wq[3];
      }
    }
  }
  float s1 = 0.f;
  #pragma unroll
  for (int i = 0; i < 16; ++i) s1 += v[i];
  #pragma unroll
  for (int m = 1; m < 16; m <<= 1) s1 += __shfl_xor(s1, m);
  const float mean = s1 * (1.0f / 256.0f);
  float s2 = 0.f;
  #pragma unroll
  for (int i = 0; i < 16; ++i) { float dd = v[i] - mean; s2 += dd * dd; }
  #pragma unroll
  for (int m = 1; m < 16; m <<= 1) s2 += __shfl_xor(s2, m);
  const float rstd = rsqrtf(s2 * (1.0f / 256.0f) + 1e-5f);
  {
    const int base = (bb * 64 + n) * 256 + dq * 16;
    #pragma unroll
    for (int i = 0; i < 16; ++i) {
      int dd = dq * 16 + i;
      outns[base + i] = (v[i] - mean) * rstd * lnss[dd] + lnsb[dd];
    }
  }
}

// ---------------- GEMM2: out = read(bf16) @ W_out (bf16 MFMA) ----------------
__global__ __launch_bounds__(512, 2) void k_gemm2(const unsigned short* __restrict__ a,
    const unsigned short* __restrict__ wot, float* __restrict__ out)
{
  __shared__ unsigned short As[128 * PAD1];
  __shared__ unsigned short Bs[256 * PAD1];
  const int tid = threadIdx.x;
  const int w = tid >> 6, lane = tid & 63;
  const int wm = w >> 2, wn = w & 3;
  const int mblk = blockIdx.x >> 2, nblk = blockIdx.x & 3;
  const int row0 = mblk * 128, n0 = nblk * 256;
  f4v zz = {0.f, 0.f, 0.f, 0.f};
  f4v acc[4][4];
  #pragma unroll
  for (int i = 0; i < 4; ++i)
    #pragma unroll
    for (int j = 0; j < 4; ++j) acc[i][j] = zz;
  const int rowA = tid >> 2, kqA = (tid & 3) * 16;
  const int colB = tid >> 1, khB = (tid & 1) * 32;
  for (int kt = 0; kt < 4; ++kt) {
    const int k0 = kt * 64;
    {
      const unsigned short* src = a + (size_t)(row0 + rowA) * 256 + k0 + kqA;
      *(s8v*)&As[rowA * PAD1 + kqA] = *(const s8v*)src;
      *(s8v*)&As[rowA * PAD1 + kqA + 8] = *(const s8v*)(src + 8);
      const unsigned short* sb = wot + (size_t)(n0 + colB) * 256 + k0 + khB;
      unsigned short* db = &Bs[colB * PAD1 + khB];
      #pragma unroll
      for (int i = 0; i < 4; ++i) *(s8v*)(db + 8 * i) = *(const s8v*)(sb + 8 * i);
    }
    __syncthreads();
    #pragma unroll
    for (int kk = 0; kk < 64; kk += 32) {
      const int kb = kk + (lane >> 4) * 8;
      s8v af[4], bf[4];
      #pragma unroll
      for (int mi = 0; mi < 4; ++mi)
        af[mi] = *(const s8v*)&As[(wm * 64 + mi * 16 + (lane & 15)) * PAD1 + kb];
      #pragma unroll
      for (int ni = 0; ni < 4; ++ni)
        bf[ni] = *(const s8v*)&Bs[(wn * 64 + ni * 16 + (lane & 15)) * PAD1 + kb];
      #pragma unroll
      for (int mi = 0; mi < 4; ++mi)
        #pragma unroll
        for (int ni = 0; ni < 4; ++ni)
          acc[mi][ni] = __builtin_amdgcn_mfma_f32_16x16x32_bf16(af[mi], bf[ni], acc[mi][ni], 0, 0, 0);
    }
    __syncthreads();
  }
  #pragma unroll
  for (int mi = 0; mi < 4; ++mi)
    #pragma unroll
    for (int j = 0; j < 4; ++j) {
      const int r = row0 + wm * 64 + mi * 16 + (lane >> 4) * 4 + j;
      #pragma unroll
      for (int ni = 0; ni < 4; ++ni) {
        const int cidx = wn * 64 + ni * 16 + (lane & 15);
        out[(size_t)r * 1024 + n0 + cidx] = acc[mi][ni][j];
      }
    }
}

extern "C" void kernel_launch(void* const* d_in, const int* in_sizes, int n_in,
                              void* d_out, int out_size, void* d_ws, size_t ws_size,
                              hipStream_t stream) {
  const float* x      = (const float*)d_in[0];
  const float* smem   = (const float*)d_in[1];
  const float* skeys  = (const float*)d_in[2];
  const float* W_in   = (const float*)d_in[3];
  const float* W_wr   = (const float*)d_in[4];
  const float* wgate  = (const float*)d_in[5];
  const float* bgate  = (const float*)d_in[6];
  const float* W_out  = (const float*)d_in[7];
  const float* lnis   = (const float*)d_in[8];
  const float* lnib   = (const float*)d_in[9];
  const float* lnss   = (const float*)d_in[10];
  const float* lnsb   = (const float*)d_in[11];
  (void)in_sizes; (void)n_in; (void)out_size; (void)ws_size;

  char* ws = (char*)d_ws;
  float*          q_buf = (float*)(ws + 0);                       // 134217728
  unsigned short* readb = (unsigned short*)(ws + 134217728);      // 16777216
  float*          summ  = (float*)(ws + 150994944);               // 2097152
  float*          wv    = (float*)(ws + 153092096);               // 2097152
  unsigned short* wth   = (unsigned short*)(ws + 155189248);      // 524288
  unsigned short* wtl   = (unsigned short*)(ws + 155713536);      // 524288
  unsigned short* wot   = (unsigned short*)(ws + 156237824);      // 524288
  float*          keyn  = (float*)(ws + 156762112);               // 65536
  float*          mrow  = (float*)(ws + 156827648);               // 131072
  float*          rrow  = (float*)(ws + 156958720);               // 131072
  float*          uvec  = (float*)(ws + 157089792);               // 1024
  float*          vvec  = (float*)(ws + 157090816);               // 1024
  float*          d0    = (float*)(ws + 157091840);               // 256
  int*            top3  = (int*)(ws + 157092096);                 // 32768
  float*          wg2   = (float*)(ws + 157124864);               // 8192
  float*          dwv   = (float*)(ws + 157133056);               // 8192

  float* out   = (float*)d_out;
  float* outns = out + 33554432;

  k_prep<<<dim3(2113), dim3(256), 0, stream>>>(W_in, lnis, lnib, W_out, skeys, smem, wgate,
                                               wth, wtl, wot, keyn, d0, uvec, vvec);
  k_stats<<<dim3(4096), dim3(256), 0, stream>>>(x, mrow, rrow);
  k_gemm1<<<dim3(256), dim3(512), 0, stream>>>(x, wth, wtl, mrow, rrow, uvec, vvec, q_buf);
  k_attn<<<dim3(1024), dim3(512), 0, stream>>>(q_buf, smem, readb, summ);
  k_match<<<dim3(512), dim3(256), 0, stream>>>(summ, keyn, W_wr, wgate, top3, wv, wg2, dwv);
  k_scan<<<dim3(8), dim3(1024), 0, stream>>>(d0, top3, wg2, dwv, bgate, wv, smem, lnss, lnsb, outns);
  k_gemm2<<<dim3(1024), dim3(512), 0, stream>>>(readb, wot, out);
}

// Round 2
// 464.752 us; speedup vs baseline: 1.0591x; 1.0591x over previous
//
#include <hip/hip_runtime.h>

typedef __attribute__((ext_vector_type(8))) short s8v;
typedef __attribute__((ext_vector_type(4))) float f4v;

#define PAD1 88
#define KP 264
#define QP 260

__device__ __forceinline__ unsigned short f2bf(float f) {
  unsigned u = __float_as_uint(f);
  u += 0x7fffu + ((u >> 16) & 1u);
  return (unsigned short)(u >> 16);
}
__device__ __forceinline__ float bf2f(unsigned short h) {
  return __uint_as_float(((unsigned)h) << 16);
}
__device__ __forceinline__ float rdlanef(float v, int l) {
  return __uint_as_float(__builtin_amdgcn_readlane(__float_as_uint(v), l));
}

// ---------------- prep: W_in'=gamma*W_in split hi/lo transposed, W_out^T bf16,
//                  u=colsum(gamma*W_in), v=beta@W_in, key_norms, d0 ----------------
__global__ void k_prep(const float* __restrict__ W_in, const float* __restrict__ lnis,
                       const float* __restrict__ lnib, const float* __restrict__ W_out,
                       const float* __restrict__ skeys, const float* __restrict__ smem0,
                       const float* __restrict__ wgate,
                       unsigned short* __restrict__ wth, unsigned short* __restrict__ wtl,
                       unsigned short* __restrict__ wot, float* __restrict__ keyn,
                       float* __restrict__ d0, float* __restrict__ uvec, float* __restrict__ vvec)
{
  __shared__ float pr[4];
  const int bid = blockIdx.x, tid = threadIdx.x;
  if (bid < 1024) {
    int idx = bid * 256 + tid;           // wt layout [n=256][k=1024]
    int n = idx >> 10, k = idx & 1023;
    float val = lnis[k] * W_in[k * 256 + n];
    unsigned short h = f2bf(val);
    wth[idx] = h;
    wtl[idx] = f2bf(val - bf2f(h));
  } else if (bid < 2048) {
    int idx = (bid - 1024) * 256 + tid;  // wot layout [n=1024][k=256]
    int n = idx >> 8, k = idx & 255;
    wot[idx] = f2bf(W_out[k * 1024 + n]);
  } else if (bid == 2048) {
    float su = 0.f, sv = 0.f;
    for (int i = 0; i < 1024; ++i) {
      float wv_ = W_in[i * 256 + tid];
      su += lnis[i] * wv_;
      sv += lnib[i] * wv_;
    }
    uvec[tid] = su; vvec[tid] = sv;
  } else {
    int n = bid - 2049;
    float sk = skeys[n * 256 + tid];
    float sq = sk * sk;
    #pragma unroll
    for (int m = 32; m; m >>= 1) sq += __shfl_xor(sq, m);
    if ((tid & 63) == 0) pr[tid >> 6] = sq;
    __syncthreads();
    float tot = pr[0] + pr[1] + pr[2] + pr[3];
    keyn[n * 256 + tid] = sk * (1.0f / fmaxf(sqrtf(tot), 1e-12f));
    float pd = smem0[n * 256 + tid] * wgate[tid];
    #pragma unroll
    for (int m = 32; m; m >>= 1) pd += __shfl_xor(pd, m);
    __syncthreads();
    if ((tid & 63) == 0) pr[tid >> 6] = pd;
    __syncthreads();
    if (tid == 0) d0[n] = pr[0] + pr[1] + pr[2] + pr[3];
  }
}

// ---------------- per-row LN stats of x ----------------
__global__ void k_stats(const float* __restrict__ x, float* __restrict__ mrow, float* __restrict__ rrow)
{
  const int r = blockIdx.x * 8 + (threadIdx.x >> 5);
  const int j = threadIdx.x & 31;
  const float* p = x + (size_t)r * 1024 + j * 32;
  float s = 0.f, ss = 0.f;
  #pragma unroll
  for (int i = 0; i < 32; i += 4) {
    f4v v = *(const f4v*)(p + i);
    s  += v[0] + v[1] + v[2] + v[3];
    ss += v[0]*v[0] + v[1]*v[1] + v[2]*v[2] + v[3]*v[3];
  }
  #pragma unroll
  for (int m = 16; m; m >>= 1) { s += __shfl_xor(s, m); ss += __shfl_xor(ss, m); }
  if (j == 0) {
    float mean = s * (1.0f / 1024.0f);
    mrow[r] = mean;
    rrow[r] = rsqrtf(ss * (1.0f / 1024.0f) - mean * mean + 1e-5f);
  }
}

// ---------------- GEMM1: q = rstd*(x @ W') - rstd*m*u + v, split-bf16 (3 MFMA passes) ----------------
__global__ __launch_bounds__(512, 2) void k_gemm1(const float* __restrict__ x,
    const unsigned short* __restrict__ wth, const unsigned short* __restrict__ wtl,
    const float* __restrict__ mrow, const float* __restrict__ rrow,
    const float* __restrict__ uvec, const float* __restrict__ vvec,
    float* __restrict__ q)
{
  __shared__ unsigned short Ah[128 * PAD1], Al[128 * PAD1];
  __shared__ unsigned short Bh[256 * PAD1], Bl[256 * PAD1];
  __shared__ float uls[256], vls[256];
  const int tid = threadIdx.x;
  const int w = tid >> 6, lane = tid & 63;
  const int wm = w >> 2, wn = w & 3;
  const int row0 = blockIdx.x * 128;
  if (tid < 256) { uls[tid] = uvec[tid]; vls[tid] = vvec[tid]; }
  f4v zz = {0.f, 0.f, 0.f, 0.f};
  f4v acc[4][4];
  #pragma unroll
  for (int i = 0; i < 4; ++i)
    #pragma unroll
    for (int j = 0; j < 4; ++j) acc[i][j] = zz;
  const int rowA = tid >> 2, kqA = (tid & 3) * 16;
  const int colB = tid >> 1, khB = (tid & 1) * 32;
  for (int kt = 0; kt < 16; ++kt) {
    const int k0 = kt * 64;
    {
      const float* src = x + (size_t)(row0 + rowA) * 1024 + k0 + kqA;
      float vv[16];
      #pragma unroll
      for (int i = 0; i < 4; ++i) *(f4v*)(vv + 4 * i) = *(const f4v*)(src + 4 * i);
      unsigned short hh[16], ll[16];
      #pragma unroll
      for (int i = 0; i < 16; ++i) {
        unsigned short hsh = f2bf(vv[i]);
        hh[i] = hsh;
        ll[i] = f2bf(vv[i] - bf2f(hsh));
      }
      unsigned short* dh = &Ah[rowA * PAD1 + kqA];
      unsigned short* dl = &Al[rowA * PAD1 + kqA];
      *(s8v*)dh = *(const s8v*)hh; *(s8v*)(dh + 8) = *(const s8v*)(hh + 8);
      *(s8v*)dl = *(const s8v*)ll; *(s8v*)(dl + 8) = *(const s8v*)(ll + 8);
      const unsigned short* sh = wth + (size_t)colB * 1024 + k0 + khB;
      const unsigned short* sl = wtl + (size_t)colB * 1024 + k0 + khB;
      unsigned short* dbh = &Bh[colB * PAD1 + khB];
      unsigned short* dbl = &Bl[colB * PAD1 + khB];
      #pragma unroll
      for (int i = 0; i < 4; ++i) {
        *(s8v*)(dbh + 8 * i) = *(const s8v*)(sh + 8 * i);
        *(s8v*)(dbl + 8 * i) = *(const s8v*)(sl + 8 * i);
      }
    }
    __syncthreads();
    #pragma unroll
    for (int kk = 0; kk < 64; kk += 32) {
      const int kb = kk + (lane >> 4) * 8;
      s8v ah[4], al[4], bh[4], bl[4];
      #pragma unroll
      for (int mi = 0; mi < 4; ++mi) {
        const int rr = (wm * 64 + mi * 16 + (lane & 15)) * PAD1 + kb;
        ah[mi] = *(const s8v*)&Ah[rr];
        al[mi] = *(const s8v*)&Al[rr];
      }
      #pragma unroll
      for (int ni = 0; ni < 4; ++ni) {
        const int ccv = (wn * 64 + ni * 16 + (lane & 15)) * PAD1 + kb;
        bh[ni] = *(const s8v*)&Bh[ccv];
        bl[ni] = *(const s8v*)&Bl[ccv];
      }
      #pragma unroll
      for (int mi = 0; mi < 4; ++mi)
        #pragma unroll
        for (int ni = 0; ni < 4; ++ni) {
          acc[mi][ni] = __builtin_amdgcn_mfma_f32_16x16x32_bf16(ah[mi], bh[ni], acc[mi][ni], 0, 0, 0);
          acc[mi][ni] = __builtin_amdgcn_mfma_f32_16x16x32_bf16(ah[mi], bl[ni], acc[mi][ni], 0, 0, 0);
          acc[mi][ni] = __builtin_amdgcn_mfma_f32_16x16x32_bf16(al[mi], bh[ni], acc[mi][ni], 0, 0, 0);
        }
    }
    __syncthreads();
  }
  #pragma unroll
  for (int mi = 0; mi < 4; ++mi)
    #pragma unroll
    for (int j = 0; j < 4; ++j) {
      const int r = row0 + wm * 64 + mi * 16 + (lane >> 4) * 4 + j;
      const float mv = mrow[r], rv = rrow[r];
      #pragma unroll
      for (int ni = 0; ni < 4; ++ni) {
        const int cidx = wn * 64 + ni * 16 + (lane & 15);
        q[(size_t)r * 256 + cidx] = rv * acc[mi][ni][j] - rv * mv * uls[cidx] + vls[cidx];
      }
    }
}

// ---------------- attention: per wave = (chunk, head). softmax over 64 slots, read (bf16) + chunk summary ----------------
__global__ __launch_bounds__(512, 2) void k_attn(const float* __restrict__ q,
    const float* __restrict__ smem0, unsigned short* __restrict__ readb,
    float* __restrict__ summ)
{
  __shared__ float ks[64 * KP];
  __shared__ float qs[2][16 * QP];
  __shared__ float as_[8][64 * 20];
  const int tid = threadIdx.x;
  const int w = tid >> 6, lane = tid & 63;
  const int cl = w >> 2, h = w & 3;
  const int g = blockIdx.x * 2 + cl;
  const int bb = g >> 8, cc = g & 255;
  const int rowbase = bb * 4096 + cc * 16;

  #pragma unroll
  for (int i = 0; i < 32; ++i) {
    int idx = i * 512 + tid;
    ks[(idx >> 8) * KP + (idx & 255)] = smem0[idx];
  }
  {
    const int c2 = tid >> 8;
    const int rr = (tid >> 4) & 15;
    const int dq = (tid & 15) * 16;
    const int g2 = blockIdx.x * 2 + c2;
    const float* src = q + (size_t)((g2 >> 8) * 4096 + (g2 & 255) * 16 + rr) * 256 + dq;
    float* dst = &qs[c2][rr * QP + dq];
    #pragma unroll
    for (int i = 0; i < 4; ++i) *(f4v*)(dst + 4 * i) = *(const f4v*)(src + 4 * i);
  }
  __syncthreads();

  float S[16];
  #pragma unroll
  for (int t = 0; t < 16; ++t) S[t] = 0.f;
  const float* qsl = qs[cl];
  const int hb = h * 64;
  for (int c4 = 0; c4 < 16; ++c4) {
    f4v kv = *(const f4v*)&ks[lane * KP + hb + c4 * 4];
    #pragma unroll
    for (int t = 0; t < 16; ++t) {
      f4v qv = *(const f4v*)&qsl[t * QP + hb + c4 * 4];
      S[t] += qv[0] * kv[0] + qv[1] * kv[1] + qv[2] * kv[2] + qv[3] * kv[3];
    }
  }
  float rsum[16];
  #pragma unroll
  for (int t = 0; t < 16; ++t) {
    float sc = S[t] * 0.125f;
    float mx = sc;
    #pragma unroll
    for (int m = 32; m; m >>= 1) mx = fmaxf(mx, __shfl_xor(mx, m));
    float p = __expf(sc - mx);
    float sm = p;
    #pragma unroll
    for (int m = 32; m; m >>= 1) sm += __shfl_xor(sm, m);
    as_[w][lane * 20 + t] = p;
    rsum[t] = 1.0f / sm;
  }
  float r[16];
  #pragma unroll
  for (int t = 0; t < 16; ++t) r[t] = 0.f;
  for (int n = 0; n < 64; ++n) {
    float kv = ks[n * KP + hb + lane];
    const float* ap = &as_[w][n * 20];
    #pragma unroll
    for (int t4 = 0; t4 < 4; ++t4) {
      f4v av = *(const f4v*)(ap + t4 * 4);
      r[t4 * 4 + 0] += av[0] * kv; r[t4 * 4 + 1] += av[1] * kv;
      r[t4 * 4 + 2] += av[2] * kv; r[t4 * 4 + 3] += av[3] * kv;
    }
  }
  float sp = 0.f;
  #pragma unroll
  for (int t = 0; t < 16; ++t) {
    float rv = r[t] * rsum[t];
    sp += rv;
    readb[(size_t)(rowbase + t) * 256 + hb + lane] = f2bf(rv);
  }
  summ[(size_t)g * 256 + hb + lane] = sp * (1.0f / 16.0f);
}

// ---------------- per-chunk: match -> top3, wv = summary@W_write, wg2 = wv.Wg2, dwv = wv.Wg1 ----------------
__global__ void k_match(const float* __restrict__ summ, const float* __restrict__ keyn,
                        const float* __restrict__ Wwr, const float* __restrict__ wgate,
                        int* __restrict__ top3, float* __restrict__ wv,
                        float* __restrict__ wg2, float* __restrict__ dwv)
{
  __shared__ float sm[4][256];
  __shared__ float nrm_inv[4];
  __shared__ float mtch[4][64];
  __shared__ float redA[4][4], redB[4][4];
  const int tid = threadIdx.x, lane = tid & 63, w = tid >> 6;
  const int gbase = blockIdx.x * 4;
  #pragma unroll
  for (int gi = 0; gi < 4; ++gi) sm[gi][tid] = summ[(size_t)(gbase + gi) * 256 + tid];
  __syncthreads();
  {
    float ss = 0.f;
    #pragma unroll
    for (int i = 0; i < 4; ++i) { float vv_ = sm[w][lane + i * 64]; ss += vv_ * vv_; }
    #pragma unroll
    for (int m = 32; m; m >>= 1) ss += __shfl_xor(ss, m);
    if (lane == 0) nrm_inv[w] = 1.0f / fmaxf(sqrtf(ss), 1e-12f);
  }
  __syncthreads();
  {
    const int n = tid >> 2, qq = tid & 3;
    float mac[4] = {0.f, 0.f, 0.f, 0.f};
    const float* kp = keyn + n * 256 + qq * 64;
    for (int d = 0; d < 64; ++d) {
      float kv = kp[d];
      int dd = qq * 64 + d;
      mac[0] += sm[0][dd] * kv; mac[1] += sm[1][dd] * kv;
      mac[2] += sm[2][dd] * kv; mac[3] += sm[3][dd] * kv;
    }
    #pragma unroll
    for (int gi = 0; gi < 4; ++gi) {
      float v2_ = mac[gi];
      v2_ += __shfl_xor(v2_, 1);
      v2_ += __shfl_xor(v2_, 2);
      if (qq == 0) mtch[gi][n] = v2_ * nrm_inv[gi];
    }
  }
  __syncthreads();
  {
    float vorig = mtch[w][lane];
    #pragma unroll
    for (int it = 0; it < 3; ++it) {
      float rv = vorig; int ri = lane;
      #pragma unroll
      for (int m = 32; m; m >>= 1) {
        float ov = __shfl_xor(rv, m); int oi = __shfl_xor(ri, m);
        if (ov > rv || (ov == rv && oi < ri)) { rv = ov; ri = oi; }
      }
      if (lane == 0) top3[(gbase + w) * 4 + it] = ri;
      if (lane == ri) vorig = -3.0e38f;
    }
  }
  float wva[4] = {0.f, 0.f, 0.f, 0.f};
  for (int d = 0; d < 256; ++d) {
    float ww = Wwr[(size_t)d * 256 + tid];
    wva[0] += sm[0][d] * ww; wva[1] += sm[1][d] * ww;
    wva[2] += sm[2][d] * ww; wva[3] += sm[3][d] * ww;
  }
  const float g1 = wgate[tid], g2 = wgate[256 + tid];
  #pragma unroll
  for (int gi = 0; gi < 4; ++gi) {
    wv[(size_t)(gbase + gi) * 256 + tid] = wva[gi];
    float p2 = wva[gi] * g2, p1 = wva[gi] * g1;
    #pragma unroll
    for (int m = 32; m; m >>= 1) { p2 += __shfl_xor(p2, m); p1 += __shfl_xor(p1, m); }
    if (lane == 0) { redA[gi][w] = p2; redB[gi][w] = p1; }
  }
  __syncthreads();
  if (tid < 4) {
    wg2[gbase + tid] = redA[tid][0] + redA[tid][1] + redA[tid][2] + redA[tid][3];
    dwv[gbase + tid] = redB[tid][0] + redB[tid][1] + redB[tid][2] + redB[tid][3];
  }
}

// ---------------- scan: register-resident gate chain (v_readlane), hit bitmasks,
//                  sparse replay via __ffsll, then LN -> new_slots ----------------
__global__ __launch_bounds__(1024) void k_scan(const float* __restrict__ d0,
    const int* __restrict__ top3, const float* __restrict__ wg2, const float* __restrict__ dwv,
    const float* __restrict__ bgate, const float* __restrict__ wv,
    const float* __restrict__ smem0, const float* __restrict__ lnss,
    const float* __restrict__ lnsb, float* __restrict__ outns)
{
  __shared__ float gls[256];
  __shared__ unsigned long long smask[64 * 4];
  const int bb = blockIdx.x, tid = threadIdx.x;

  if (tid < 64) {
    const int lane = tid;
    const float bg = bgate[0];
    int ix[4], iy[4], iz[4];
    float wgb[4], dwvv[4], gout[4];
    unsigned long long mk[4];
    #pragma unroll
    for (int j = 0; j < 4; ++j) {
      const int c = j * 64 + lane;
      ix[j] = top3[bb * 1024 + c * 4 + 0];
      iy[j] = top3[bb * 1024 + c * 4 + 1];
      iz[j] = top3[bb * 1024 + c * 4 + 2];
      wgb[j] = wg2[bb * 256 + c] + bg;
      dwvv[j] = dwv[bb * 256 + c];
      mk[j] = 0ull;
      gout[j] = 0.f;
    }
    float dn = d0[lane];
    #pragma unroll
    for (int c = 0; c < 256; ++c) {
      const int j = c >> 6, sl = c & 63;
      const int i0 = __builtin_amdgcn_readlane(ix[j], sl);
      const int i1 = __builtin_amdgcn_readlane(iy[j], sl);
      const int i2 = __builtin_amdgcn_readlane(iz[j], sl);
      const float wz = rdlanef(wgb[j], sl);
      const float dv = rdlanef(dwvv[j], sl);
      const float s3 = rdlanef(dn, i0) + rdlanef(dn, i1) + rdlanef(dn, i2);
      const float z = s3 * (1.0f / 3.0f) + wz;
      const float gv = 1.0f / (1.0f + __expf(-z));
      if (lane == sl) gout[j] = gv;
      const bool hit = (lane == i0) | (lane == i1) | (lane == i2);
      mk[j] |= ((unsigned long long)hit) << sl;
      dn = hit ? (1.0f - gv) * dn + gv * dv : dn;
    }
    #pragma unroll
    for (int j = 0; j < 4; ++j) {
      gls[j * 64 + lane] = gout[j];
      smask[lane * 4 + j] = mk[j];
    }
  }
  __syncthreads();

  const int n = tid >> 4, dq = tid & 15;
  float v[16];
  {
    const float* p = smem0 + n * 256 + dq * 16;
    #pragma unroll
    for (int i = 0; i < 16; i += 4) *(f4v*)(v + i) = *(const f4v*)(p + i);
  }
  #pragma unroll
  for (int j = 0; j < 4; ++j) {
    unsigned long long m = smask[n * 4 + j];
    while (m) {
      const int b = __ffsll(m) - 1;
      m &= (m - 1);
      const int c = j * 64 + b;
      const float gv = gls[c];
      const float om = 1.0f - gv;
      const float* wvp = wv + (size_t)(bb * 256 + c) * 256 + dq * 16;
      #pragma unroll
      for (int i4 = 0; i4 < 4; ++i4) {
        f4v wq = *(const f4v*)(wvp + i4 * 4);
        v[i4 * 4 + 0] = om * v[i4 * 4 + 0] + gv * wq[0];
        v[i4 * 4 + 1] = om * v[i4 * 4 + 1] + gv * wq[1];
        v[i4 * 4 + 2] = om * v[i4 * 4 + 2] + gv * wq[2];
        v[i4 * 4 + 3] = om * v[i4 * 4 + 3] + gv * wq[3];
      }
    }
  }
  float s1 = 0.f;
  #pragma unroll
  for (int i = 0; i < 16; ++i) s1 += v[i];
  #pragma unroll
  for (int m = 1; m < 16; m <<= 1) s1 += __shfl_xor(s1, m);
  const float mean = s1 * (1.0f / 256.0f);
  float s2 = 0.f;
  #pragma unroll
  for (int i = 0; i < 16; ++i) { float dd = v[i] - mean; s2 += dd * dd; }
  #pragma unroll
  for (int m = 1; m < 16; m <<= 1) s2 += __shfl_xor(s2, m);
  const float rstd = rsqrtf(s2 * (1.0f / 256.0f) + 1e-5f);
  {
    const int base = (bb * 64 + n) * 256 + dq * 16;
    #pragma unroll
    for (int i = 0; i < 16; ++i) {
      int dd = dq * 16 + i;
      outns[base + i] = (v[i] - mean) * rstd * lnss[dd] + lnsb[dd];
    }
  }
}

// ---------------- GEMM2: out = read(bf16) @ W_out (bf16 MFMA) ----------------
__global__ __launch_bounds__(512, 2) void k_gemm2(const unsigned short* __restrict__ a,
    const unsigned short* __restrict__ wot, float* __restrict__ out)
{
  __shared__ unsigned short As[128 * PAD1];
  __shared__ unsigned short Bs[256 * PAD1];
  const int tid = threadIdx.x;
  const int w = tid >> 6, lane = tid & 63;
  const int wm = w >> 2, wn = w & 3;
  const int mblk = blockIdx.x >> 2, nblk = blockIdx.x & 3;
  const int row0 = mblk * 128, n0 = nblk * 256;
  f4v zz = {0.f, 0.f, 0.f, 0.f};
  f4v acc[4][4];
  #pragma unroll
  for (int i = 0; i < 4; ++i)
    #pragma unroll
    for (int j = 0; j < 4; ++j) acc[i][j] = zz;
  const int rowA = tid >> 2, kqA = (tid & 3) * 16;
  const int colB = tid >> 1, khB = (tid & 1) * 32;
  for (int kt = 0; kt < 4; ++kt) {
    const int k0 = kt * 64;
    {
      const unsigned short* src = a + (size_t)(row0 + rowA) * 256 + k0 + kqA;
      *(s8v*)&As[rowA * PAD1 + kqA] = *(const s8v*)src;
      *(s8v*)&As[rowA * PAD1 + kqA + 8] = *(const s8v*)(src + 8);
      const unsigned short* sb = wot + (size_t)(n0 + colB) * 256 + k0 + khB;
      unsigned short* db = &Bs[colB * PAD1 + khB];
      #pragma unroll
      for (int i = 0; i < 4; ++i) *(s8v*)(db + 8 * i) = *(const s8v*)(sb + 8 * i);
    }
    __syncthreads();
    #pragma unroll
    for (int kk = 0; kk < 64; kk += 32) {
      const int kb = kk + (lane >> 4) * 8;
      s8v af[4], bf[4];
      #pragma unroll
      for (int mi = 0; mi < 4; ++mi)
        af[mi] = *(const s8v*)&As[(wm * 64 + mi * 16 + (lane & 15)) * PAD1 + kb];
      #pragma unroll
      for (int ni = 0; ni < 4; ++ni)
        bf[ni] = *(const s8v*)&Bs[(wn * 64 + ni * 16 + (lane & 15)) * PAD1 + kb];
      #pragma unroll
      for (int mi = 0; mi < 4; ++mi)
        #pragma unroll
        for (int ni = 0; ni < 4; ++ni)
          acc[mi][ni] = __builtin_amdgcn_mfma_f32_16x16x32_bf16(af[mi], bf[ni], acc[mi][ni], 0, 0, 0);
    }
    __syncthreads();
  }
  #pragma unroll
  for (int mi = 0; mi < 4; ++mi)
    #pragma unroll
    for (int j = 0; j < 4; ++j) {
      const int r = row0 + wm * 64 + mi * 16 + (lane >> 4) * 4 + j;
      #pragma unroll
      for (int ni = 0; ni < 4; ++ni) {
        const int cidx = wn * 64 + ni * 16 + (lane & 15);
        out[(size_t)r * 1024 + n0 + cidx] = acc[mi][ni][j];
      }
    }
}

extern "C" void kernel_launch(void* const* d_in, const int* in_sizes, int n_in,
                              void* d_out, int out_size, void* d_ws, size_t ws_size,
                              hipStream_t stream) {
  const float* x      = (const float*)d_in[0];
  const float* smem   = (const float*)d_in[1];
  const float* skeys  = (const float*)d_in[2];
  const float* W_in   = (const float*)d_in[3];
  const float* W_wr   = (const float*)d_in[4];
  const float* wgate  = (const float*)d_in[5];
  const float* bgate  = (const float*)d_in[6];
  const float* W_out  = (const float*)d_in[7];
  const float* lnis   = (const float*)d_in[8];
  const float* lnib   = (const float*)d_in[9];
  const float* lnss   = (const float*)d_in[10];
  const float* lnsb   = (const float*)d_in[11];
  (void)in_sizes; (void)n_in; (void)out_size; (void)ws_size;

  char* ws = (char*)d_ws;
  float*          q_buf = (float*)(ws + 0);                       // 134217728
  unsigned short* readb = (unsigned short*)(ws + 134217728);      // 16777216
  float*          summ  = (float*)(ws + 150994944);               // 2097152
  float*          wv    = (float*)(ws + 153092096);               // 2097152
  unsigned short* wth   = (unsigned short*)(ws + 155189248);      // 524288
  unsigned short* wtl   = (unsigned short*)(ws + 155713536);      // 524288
  unsigned short* wot   = (unsigned short*)(ws + 156237824);      // 524288
  float*          keyn  = (float*)(ws + 156762112);               // 65536
  float*          mrow  = (float*)(ws + 156827648);               // 131072
  float*          rrow  = (float*)(ws + 156958720);               // 131072
  float*          uvec  = (float*)(ws + 157089792);               // 1024
  float*          vvec  = (float*)(ws + 157090816);               // 1024
  float*          d0    = (float*)(ws + 157091840);               // 256
  int*            top3  = (int*)(ws + 157092096);                 // 32768
  float*          wg2   = (float*)(ws + 157124864);               // 8192
  float*          dwv   = (float*)(ws + 157133056);               // 8192

  float* out   = (float*)d_out;
  float* outns = out + 33554432;

  k_prep<<<dim3(2113), dim3(256), 0, stream>>>(W_in, lnis, lnib, W_out, skeys, smem, wgate,
                                               wth, wtl, wot, keyn, d0, uvec, vvec);
  k_stats<<<dim3(4096), dim3(256), 0, stream>>>(x, mrow, rrow);
  k_gemm1<<<dim3(256), dim3(512), 0, stream>>>(x, wth, wtl, mrow, rrow, uvec, vvec, q_buf);
  k_attn<<<dim3(1024), dim3(512), 0, stream>>>(q_buf, smem, readb, summ);
  k_match<<<dim3(512), dim3(256), 0, stream>>>(summ, keyn, W_wr, wgate, top3, wv, wg2, dwv);
  k_scan<<<dim3(8), dim3(1024), 0, stream>>>(d0, top3, wg2, dwv, bgate, wv, smem, lnss, lnsb, outns);
  k_gemm2<<<dim3(1024), dim3(512), 0, stream>>>(readb, wot, out);
}

// Round 3
// 453.440 us; speedup vs baseline: 1.0855x; 1.0249x over previous
//
#include <hip/hip_runtime.h>

typedef __attribute__((ext_vector_type(8))) short s8v;
typedef __attribute__((ext_vector_type(4))) float f4v;

#define PAD1 88
#define KP 264
#define QP 260

__device__ __forceinline__ unsigned short f2bf(float f) {
  unsigned u = __float_as_uint(f);
  u += 0x7fffu + ((u >> 16) & 1u);
  return (unsigned short)(u >> 16);
}
__device__ __forceinline__ float bf2f(unsigned short h) {
  return __uint_as_float(((unsigned)h) << 16);
}
__device__ __forceinline__ float rdlanef(float v, int l) {
  return __uint_as_float(__builtin_amdgcn_readlane(__float_as_uint(v), l));
}

// ---------------- prep: W_in'=gamma*W_in split hi/lo transposed, W_out^T bf16,
//                  u=colsum(gamma*W_in), v=beta@W_in, key_norms, d0 ----------------
__global__ void k_prep(const float* __restrict__ W_in, const float* __restrict__ lnis,
                       const float* __restrict__ lnib, const float* __restrict__ W_out,
                       const float* __restrict__ skeys, const float* __restrict__ smem0,
                       const float* __restrict__ wgate,
                       unsigned short* __restrict__ wth, unsigned short* __restrict__ wtl,
                       unsigned short* __restrict__ wot, float* __restrict__ keyn,
                       float* __restrict__ d0, float* __restrict__ uvec, float* __restrict__ vvec)
{
  __shared__ float pr[4];
  const int bid = blockIdx.x, tid = threadIdx.x;
  if (bid < 1024) {
    int idx = bid * 256 + tid;           // wt layout [n=256][k=1024]
    int n = idx >> 10, k = idx & 1023;
    float val = lnis[k] * W_in[k * 256 + n];
    unsigned short h = f2bf(val);
    wth[idx] = h;
    wtl[idx] = f2bf(val - bf2f(h));
  } else if (bid < 2048) {
    int idx = (bid - 1024) * 256 + tid;  // wot layout [n=1024][k=256]
    int n = idx >> 8, k = idx & 255;
    wot[idx] = f2bf(W_out[k * 1024 + n]);
  } else if (bid == 2048) {
    float su = 0.f, sv = 0.f;
    for (int i = 0; i < 1024; ++i) {
      float wv_ = W_in[i * 256 + tid];
      su += lnis[i] * wv_;
      sv += lnib[i] * wv_;
    }
    uvec[tid] = su; vvec[tid] = sv;
  } else {
    int n = bid - 2049;
    float sk = skeys[n * 256 + tid];
    float sq = sk * sk;
    #pragma unroll
    for (int m = 32; m; m >>= 1) sq += __shfl_xor(sq, m);
    if ((tid & 63) == 0) pr[tid >> 6] = sq;
    __syncthreads();
    float tot = pr[0] + pr[1] + pr[2] + pr[3];
    keyn[n * 256 + tid] = sk * (1.0f / fmaxf(sqrtf(tot), 1e-12f));
    float pd = smem0[n * 256 + tid] * wgate[tid];
    #pragma unroll
    for (int m = 32; m; m >>= 1) pd += __shfl_xor(pd, m);
    __syncthreads();
    if ((tid & 63) == 0) pr[tid >> 6] = pd;
    __syncthreads();
    if (tid == 0) d0[n] = pr[0] + pr[1] + pr[2] + pr[3];
  }
}

// ---------------- per-row LN stats of x ----------------
__global__ void k_stats(const float* __restrict__ x, float* __restrict__ mrow, float* __restrict__ rrow)
{
  const int r = blockIdx.x * 8 + (threadIdx.x >> 5);
  const int j = threadIdx.x & 31;
  const float* p = x + (size_t)r * 1024 + j * 32;
  float s = 0.f, ss = 0.f;
  #pragma unroll
  for (int i = 0; i < 32; i += 4) {
    f4v v = *(const f4v*)(p + i);
    s  += v[0] + v[1] + v[2] + v[3];
    ss += v[0]*v[0] + v[1]*v[1] + v[2]*v[2] + v[3]*v[3];
  }
  #pragma unroll
  for (int m = 16; m; m >>= 1) { s += __shfl_xor(s, m); ss += __shfl_xor(ss, m); }
  if (j == 0) {
    float mean = s * (1.0f / 1024.0f);
    mrow[r] = mean;
    rrow[r] = rsqrtf(ss * (1.0f / 1024.0f) - mean * mean + 1e-5f);
  }
}

// ---------------- GEMM1: q = rstd*(x @ W') - rstd*m*u + v, split-bf16 (3 MFMA passes) ----------------
__global__ __launch_bounds__(512, 2) void k_gemm1(const float* __restrict__ x,
    const unsigned short* __restrict__ wth, const unsigned short* __restrict__ wtl,
    const float* __restrict__ mrow, const float* __restrict__ rrow,
    const float* __restrict__ uvec, const float* __restrict__ vvec,
    float* __restrict__ q)
{
  __shared__ unsigned short Ah[128 * PAD1], Al[128 * PAD1];
  __shared__ unsigned short Bh[256 * PAD1], Bl[256 * PAD1];
  __shared__ float uls[256], vls[256];
  const int tid = threadIdx.x;
  const int w = tid >> 6, lane = tid & 63;
  const int wm = w >> 2, wn = w & 3;
  const int row0 = blockIdx.x * 128;
  if (tid < 256) { uls[tid] = uvec[tid]; vls[tid] = vvec[tid]; }
  f4v zz = {0.f, 0.f, 0.f, 0.f};
  f4v acc[4][4];
  #pragma unroll
  for (int i = 0; i < 4; ++i)
    #pragma unroll
    for (int j = 0; j < 4; ++j) acc[i][j] = zz;
  const int rowA = tid >> 2, kqA = (tid & 3) * 16;
  const int colB = tid >> 1, khB = (tid & 1) * 32;
  for (int kt = 0; kt < 16; ++kt) {
    const int k0 = kt * 64;
    {
      const float* src = x + (size_t)(row0 + rowA) * 1024 + k0 + kqA;
      float vv[16];
      #pragma unroll
      for (int i = 0; i < 4; ++i) *(f4v*)(vv + 4 * i) = *(const f4v*)(src + 4 * i);
      unsigned short hh[16], ll[16];
      #pragma unroll
      for (int i = 0; i < 16; ++i) {
        unsigned short hsh = f2bf(vv[i]);
        hh[i] = hsh;
        ll[i] = f2bf(vv[i] - bf2f(hsh));
      }
      unsigned short* dh = &Ah[rowA * PAD1 + kqA];
      unsigned short* dl = &Al[rowA * PAD1 + kqA];
      *(s8v*)dh = *(const s8v*)hh; *(s8v*)(dh + 8) = *(const s8v*)(hh + 8);
      *(s8v*)dl = *(const s8v*)ll; *(s8v*)(dl + 8) = *(const s8v*)(ll + 8);
      const unsigned short* sh = wth + (size_t)colB * 1024 + k0 + khB;
      const unsigned short* sl = wtl + (size_t)colB * 1024 + k0 + khB;
      unsigned short* dbh = &Bh[colB * PAD1 + khB];
      unsigned short* dbl = &Bl[colB * PAD1 + khB];
      #pragma unroll
      for (int i = 0; i < 4; ++i) {
        *(s8v*)(dbh + 8 * i) = *(const s8v*)(sh + 8 * i);
        *(s8v*)(dbl + 8 * i) = *(const s8v*)(sl + 8 * i);
      }
    }
    __syncthreads();
    #pragma unroll
    for (int kk = 0; kk < 64; kk += 32) {
      const int kb = kk + (lane >> 4) * 8;
      s8v ah[4], al[4], bh[4], bl[4];
      #pragma unroll
      for (int mi = 0; mi < 4; ++mi) {
        const int rr = (wm * 64 + mi * 16 + (lane & 15)) * PAD1 + kb;
        ah[mi] = *(const s8v*)&Ah[rr];
        al[mi] = *(const s8v*)&Al[rr];
      }
      #pragma unroll
      for (int ni = 0; ni < 4; ++ni) {
        const int ccv = (wn * 64 + ni * 16 + (lane & 15)) * PAD1 + kb;
        bh[ni] = *(const s8v*)&Bh[ccv];
        bl[ni] = *(const s8v*)&Bl[ccv];
      }
      #pragma unroll
      for (int mi = 0; mi < 4; ++mi)
        #pragma unroll
        for (int ni = 0; ni < 4; ++ni) {
          acc[mi][ni] = __builtin_amdgcn_mfma_f32_16x16x32_bf16(ah[mi], bh[ni], acc[mi][ni], 0, 0, 0);
          acc[mi][ni] = __builtin_amdgcn_mfma_f32_16x16x32_bf16(ah[mi], bl[ni], acc[mi][ni], 0, 0, 0);
          acc[mi][ni] = __builtin_amdgcn_mfma_f32_16x16x32_bf16(al[mi], bh[ni], acc[mi][ni], 0, 0, 0);
        }
    }
    __syncthreads();
  }
  #pragma unroll
  for (int mi = 0; mi < 4; ++mi)
    #pragma unroll
    for (int j = 0; j < 4; ++j) {
      const int r = row0 + wm * 64 + mi * 16 + (lane >> 4) * 4 + j;
      const float mv = mrow[r], rv = rrow[r];
      #pragma unroll
      for (int ni = 0; ni < 4; ++ni) {
        const int cidx = wn * 64 + ni * 16 + (lane & 15);
        q[(size_t)r * 256 + cidx] = rv * acc[mi][ni][j] - rv * mv * uls[cidx] + vls[cidx];
      }
    }
}

// ---------------- attention: per wave = (chunk, head). softmax over 64 slots, read (bf16) + chunk summary ----------------
__global__ __launch_bounds__(512, 2) void k_attn(const float* __restrict__ q,
    const float* __restrict__ smem0, unsigned short* __restrict__ readb,
    float* __restrict__ summ)
{
  __shared__ float ks[64 * KP];
  __shared__ float qs[2][16 * QP];
  __shared__ float as_[8][64 * 20];
  const int tid = threadIdx.x;
  const int w = tid >> 6, lane = tid & 63;
  const int cl = w >> 2, h = w & 3;
  const int g = blockIdx.x * 2 + cl;
  const int bb = g >> 8, cc = g & 255;
  const int rowbase = bb * 4096 + cc * 16;

  #pragma unroll
  for (int i = 0; i < 32; ++i) {
    int idx = i * 512 + tid;
    ks[(idx >> 8) * KP + (idx & 255)] = smem0[idx];
  }
  {
    const int c2 = tid >> 8;
    const int rr = (tid >> 4) & 15;
    const int dq = (tid & 15) * 16;
    const int g2 = blockIdx.x * 2 + c2;
    const float* src = q + (size_t)((g2 >> 8) * 4096 + (g2 & 255) * 16 + rr) * 256 + dq;
    float* dst = &qs[c2][rr * QP + dq];
    #pragma unroll
    for (int i = 0; i < 4; ++i) *(f4v*)(dst + 4 * i) = *(const f4v*)(src + 4 * i);
  }
  __syncthreads();

  float S[16];
  #pragma unroll
  for (int t = 0; t < 16; ++t) S[t] = 0.f;
  const float* qsl = qs[cl];
  const int hb = h * 64;
  for (int c4 = 0; c4 < 16; ++c4) {
    f4v kv = *(const f4v*)&ks[lane * KP + hb + c4 * 4];
    #pragma unroll
    for (int t = 0; t < 16; ++t) {
      f4v qv = *(const f4v*)&qsl[t * QP + hb + c4 * 4];
      S[t] += qv[0] * kv[0] + qv[1] * kv[1] + qv[2] * kv[2] + qv[3] * kv[3];
    }
  }
  float rsum[16];
  #pragma unroll
  for (int t = 0; t < 16; ++t) {
    float sc = S[t] * 0.125f;
    float mx = sc;
    #pragma unroll
    for (int m = 32; m; m >>= 1) mx = fmaxf(mx, __shfl_xor(mx, m));
    float p = __expf(sc - mx);
    float sm = p;
    #pragma unroll
    for (int m = 32; m; m >>= 1) sm += __shfl_xor(sm, m);
    as_[w][lane * 20 + t] = p;
    rsum[t] = 1.0f / sm;
  }
  float r[16];
  #pragma unroll
  for (int t = 0; t < 16; ++t) r[t] = 0.f;
  for (int n = 0; n < 64; ++n) {
    float kv = ks[n * KP + hb + lane];
    const float* ap = &as_[w][n * 20];
    #pragma unroll
    for (int t4 = 0; t4 < 4; ++t4) {
      f4v av = *(const f4v*)(ap + t4 * 4);
      r[t4 * 4 + 0] += av[0] * kv; r[t4 * 4 + 1] += av[1] * kv;
      r[t4 * 4 + 2] += av[2] * kv; r[t4 * 4 + 3] += av[3] * kv;
    }
  }
  float sp = 0.f;
  #pragma unroll
  for (int t = 0; t < 16; ++t) {
    float rv = r[t] * rsum[t];
    sp += rv;
    readb[(size_t)(rowbase + t) * 256 + hb + lane] = f2bf(rv);
  }
  summ[(size_t)g * 256 + hb + lane] = sp * (1.0f / 16.0f);
}

// ---------------- per-chunk: match -> top3, wv = summary@W_write, wg2 = wv.Wg2, dwv = wv.Wg1 ----------------
__global__ void k_match(const float* __restrict__ summ, const float* __restrict__ keyn,
                        const float* __restrict__ Wwr, const float* __restrict__ wgate,
                        int* __restrict__ top3, float* __restrict__ wv,
                        float* __restrict__ wg2, float* __restrict__ dwv)
{
  __shared__ float sm[4][256];
  __shared__ float nrm_inv[4];
  __shared__ float mtch[4][64];
  __shared__ float redA[4][4], redB[4][4];
  const int tid = threadIdx.x, lane = tid & 63, w = tid >> 6;
  const int gbase = blockIdx.x * 4;
  #pragma unroll
  for (int gi = 0; gi < 4; ++gi) sm[gi][tid] = summ[(size_t)(gbase + gi) * 256 + tid];
  __syncthreads();
  {
    float ss = 0.f;
    #pragma unroll
    for (int i = 0; i < 4; ++i) { float vv_ = sm[w][lane + i * 64]; ss += vv_ * vv_; }
    #pragma unroll
    for (int m = 32; m; m >>= 1) ss += __shfl_xor(ss, m);
    if (lane == 0) nrm_inv[w] = 1.0f / fmaxf(sqrtf(ss), 1e-12f);
  }
  __syncthreads();
  {
    const int n = tid >> 2, qq = tid & 3;
    float mac[4] = {0.f, 0.f, 0.f, 0.f};
    const float* kp = keyn + n * 256 + qq * 64;
    for (int d = 0; d < 64; ++d) {
      float kv = kp[d];
      int dd = qq * 64 + d;
      mac[0] += sm[0][dd] * kv; mac[1] += sm[1][dd] * kv;
      mac[2] += sm[2][dd] * kv; mac[3] += sm[3][dd] * kv;
    }
    #pragma unroll
    for (int gi = 0; gi < 4; ++gi) {
      float v2_ = mac[gi];
      v2_ += __shfl_xor(v2_, 1);
      v2_ += __shfl_xor(v2_, 2);
      if (qq == 0) mtch[gi][n] = v2_ * nrm_inv[gi];
    }
  }
  __syncthreads();
  {
    float vorig = mtch[w][lane];
    #pragma unroll
    for (int it = 0; it < 3; ++it) {
      float rv = vorig; int ri = lane;
      #pragma unroll
      for (int m = 32; m; m >>= 1) {
        float ov = __shfl_xor(rv, m); int oi = __shfl_xor(ri, m);
        if (ov > rv || (ov == rv && oi < ri)) { rv = ov; ri = oi; }
      }
      if (lane == 0) top3[(gbase + w) * 4 + it] = ri;
      if (lane == ri) vorig = -3.0e38f;
    }
  }
  float wva[4] = {0.f, 0.f, 0.f, 0.f};
  for (int d = 0; d < 256; ++d) {
    float ww = Wwr[(size_t)d * 256 + tid];
    wva[0] += sm[0][d] * ww; wva[1] += sm[1][d] * ww;
    wva[2] += sm[2][d] * ww; wva[3] += sm[3][d] * ww;
  }
  const float g1 = wgate[tid], g2 = wgate[256 + tid];
  #pragma unroll
  for (int gi = 0; gi < 4; ++gi) {
    wv[(size_t)(gbase + gi) * 256 + tid] = wva[gi];
    float p2 = wva[gi] * g2, p1 = wva[gi] * g1;
    #pragma unroll
    for (int m = 32; m; m >>= 1) { p2 += __shfl_xor(p2, m); p1 += __shfl_xor(p1, m); }
    if (lane == 0) { redA[gi][w] = p2; redB[gi][w] = p1; }
  }
  __syncthreads();
  if (tid < 4) {
    wg2[gbase + tid] = redA[tid][0] + redA[tid][1] + redA[tid][2] + redA[tid][3];
    dwv[gbase + tid] = redB[tid][0] + redB[tid][1] + redB[tid][2] + redB[tid][3];
  }
}

// ---------------- scan: register-resident gate chain, ROLLED inner loop (I-cache resident),
//                  dynamic-index v_readlane; hit bitmasks; sparse replay; LN ----------------
__global__ __launch_bounds__(1024) void k_scan(const float* __restrict__ d0,
    const int* __restrict__ top3, const float* __restrict__ wg2, const float* __restrict__ dwv,
    const float* __restrict__ bgate, const float* __restrict__ wv,
    const float* __restrict__ smem0, const float* __restrict__ lnss,
    const float* __restrict__ lnsb, float* __restrict__ outns)
{
  __shared__ float gls[256];
  __shared__ unsigned long long smask[64 * 4];
  const int bb = blockIdx.x, tid = threadIdx.x;

  if (tid < 64) {
    const int lane = tid;
    const float bg = bgate[0];
    float dn = d0[lane];
    #pragma unroll
    for (int j = 0; j < 4; ++j) {
      const int c0 = j * 64;
      const int4 t3 = *(const int4*)&top3[(bb * 256 + c0 + lane) * 4];
      const int ixj = t3.x, iyj = t3.y, izj = t3.z;
      const float wzj = wg2[bb * 256 + c0 + lane] + bg;
      const float dvj = dwv[bb * 256 + c0 + lane];
      unsigned long long mkj = 0ull;
      float gout = 0.f;
      #pragma unroll 1
      for (int sl = 0; sl < 64; ++sl) {
        const int i0 = __builtin_amdgcn_readlane(ixj, sl);
        const int i1 = __builtin_amdgcn_readlane(iyj, sl);
        const int i2 = __builtin_amdgcn_readlane(izj, sl);
        const float wz = rdlanef(wzj, sl);
        const float dv = rdlanef(dvj, sl);
        const float s3 = rdlanef(dn, i0) + rdlanef(dn, i1) + rdlanef(dn, i2);
        const float z = s3 * (1.0f / 3.0f) + wz;
        const float gv = 1.0f / (1.0f + __expf(-z));
        if (lane == sl) gout = gv;
        const bool hit = (lane == i0) | (lane == i1) | (lane == i2);
        mkj |= ((unsigned long long)hit) << sl;
        dn = hit ? (1.0f - gv) * dn + gv * dv : dn;
      }
      gls[c0 + lane] = gout;
      smask[lane * 4 + j] = mkj;
    }
  }
  __syncthreads();

  const int n = tid >> 4, dq = tid & 15;
  float v[16];
  {
    const float* p = smem0 + n * 256 + dq * 16;
    #pragma unroll
    for (int i = 0; i < 16; i += 4) *(f4v*)(v + i) = *(const f4v*)(p + i);
  }
  #pragma unroll
  for (int j = 0; j < 4; ++j) {
    unsigned long long m = smask[n * 4 + j];
    while (m) {
      const int b = __ffsll(m) - 1;
      m &= (m - 1);
      const int c = j * 64 + b;
      const float gv = gls[c];
      const float om = 1.0f - gv;
      const float* wvp = wv + (size_t)(bb * 256 + c) * 256 + dq * 16;
      #pragma unroll
      for (int i4 = 0; i4 < 4; ++i4) {
        f4v wq = *(const f4v*)(wvp + i4 * 4);
        v[i4 * 4 + 0] = om * v[i4 * 4 + 0] + gv * wq[0];
        v[i4 * 4 + 1] = om * v[i4 * 4 + 1] + gv * wq[1];
        v[i4 * 4 + 2] = om * v[i4 * 4 + 2] + gv * wq[2];
        v[i4 * 4 + 3] = om * v[i4 * 4 + 3] + gv * wq[3];
      }
    }
  }
  float s1 = 0.f;
  #pragma unroll
  for (int i = 0; i < 16; ++i) s1 += v[i];
  #pragma unroll
  for (int m = 1; m < 16; m <<= 1) s1 += __shfl_xor(s1, m);
  const float mean = s1 * (1.0f / 256.0f);
  float s2 = 0.f;
  #pragma unroll
  for (int i = 0; i < 16; ++i) { float dd = v[i] - mean; s2 += dd * dd; }
  #pragma unroll
  for (int m = 1; m < 16; m <<= 1) s2 += __shfl_xor(s2, m);
  const float rstd = rsqrtf(s2 * (1.0f / 256.0f) + 1e-5f);
  {
    const int base = (bb * 64 + n) * 256 + dq * 16;
    #pragma unroll
    for (int i = 0; i < 16; ++i) {
      int dd = dq * 16 + i;
      outns[base + i] = (v[i] - mean) * rstd * lnss[dd] + lnsb[dd];
    }
  }
}

// ---------------- GEMM2: out = read(bf16) @ W_out (bf16 MFMA) ----------------
__global__ __launch_bounds__(512, 2) void k_gemm2(const unsigned short* __restrict__ a,
    const unsigned short* __restrict__ wot, float* __restrict__ out)
{
  __shared__ unsigned short As[128 * PAD1];
  __shared__ unsigned short Bs[256 * PAD1];
  const int tid = threadIdx.x;
  const int w = tid >> 6, lane = tid & 63;
  const int wm = w >> 2, wn = w & 3;
  const int mblk = blockIdx.x >> 2, nblk = blockIdx.x & 3;
  const int row0 = mblk * 128, n0 = nblk * 256;
  f4v zz = {0.f, 0.f, 0.f, 0.f};
  f4v acc[4][4];
  #pragma unroll
  for (int i = 0; i < 4; ++i)
    #pragma unroll
    for (int j = 0; j < 4; ++j) acc[i][j] = zz;
  const int rowA = tid >> 2, kqA = (tid & 3) * 16;
  const int colB = tid >> 1, khB = (tid & 1) * 32;
  for (int kt = 0; kt < 4; ++kt) {
    const int k0 = kt * 64;
    {
      const unsigned short* src = a + (size_t)(row0 + rowA) * 256 + k0 + kqA;
      *(s8v*)&As[rowA * PAD1 + kqA] = *(const s8v*)src;
      *(s8v*)&As[rowA * PAD1 + kqA + 8] = *(const s8v*)(src + 8);
      const unsigned short* sb = wot + (size_t)(n0 + colB) * 256 + k0 + khB;
      unsigned short* db = &Bs[colB * PAD1 + khB];
      #pragma unroll
      for (int i = 0; i < 4; ++i) *(s8v*)(db + 8 * i) = *(const s8v*)(sb + 8 * i);
    }
    __syncthreads();
    #pragma unroll
    for (int kk = 0; kk < 64; kk += 32) {
      const int kb = kk + (lane >> 4) * 8;
      s8v af[4], bf[4];
      #pragma unroll
      for (int mi = 0; mi < 4; ++mi)
        af[mi] = *(const s8v*)&As[(wm * 64 + mi * 16 + (lane & 15)) * PAD1 + kb];
      #pragma unroll
      for (int ni = 0; ni < 4; ++ni)
        bf[ni] = *(const s8v*)&Bs[(wn * 64 + ni * 16 + (lane & 15)) * PAD1 + kb];
      #pragma unroll
      for (int mi = 0; mi < 4; ++mi)
        #pragma unroll
        for (int ni = 0; ni < 4; ++ni)
          acc[mi][ni] = __builtin_amdgcn_mfma_f32_16x16x32_bf16(af[mi], bf[ni], acc[mi][ni], 0, 0, 0);
    }
    __syncthreads();
  }
  #pragma unroll
  for (int mi = 0; mi < 4; ++mi)
    #pragma unroll
    for (int j = 0; j < 4; ++j) {
      const int r = row0 + wm * 64 + mi * 16 + (lane >> 4) * 4 + j;
      #pragma unroll
      for (int ni = 0; ni < 4; ++ni) {
        const int cidx = wn * 64 + ni * 16 + (lane & 15);
        out[(size_t)r * 1024 + n0 + cidx] = acc[mi][ni][j];
      }
    }
}

extern "C" void kernel_launch(void* const* d_in, const int* in_sizes, int n_in,
                              void* d_out, int out_size, void* d_ws, size_t ws_size,
                              hipStream_t stream) {
  const float* x      = (const float*)d_in[0];
  const float* smem   = (const float*)d_in[1];
  const float* skeys  = (const float*)d_in[2];
  const float* W_in   = (const float*)d_in[3];
  const float* W_wr   = (const float*)d_in[4];
  const float* wgate  = (const float*)d_in[5];
  const float* bgate  = (const float*)d_in[6];
  const float* W_out  = (const float*)d_in[7];
  const float* lnis   = (const float*)d_in[8];
  const float* lnib   = (const float*)d_in[9];
  const float* lnss   = (const float*)d_in[10];
  const float* lnsb   = (const float*)d_in[11];
  (void)in_sizes; (void)n_in; (void)out_size; (void)ws_size;

  char* ws = (char*)d_ws;
  float*          q_buf = (float*)(ws + 0);                       // 134217728
  unsigned short* readb = (unsigned short*)(ws + 134217728);      // 16777216
  float*          summ  = (float*)(ws + 150994944);               // 2097152
  float*          wv    = (float*)(ws + 153092096);               // 2097152
  unsigned short* wth   = (unsigned short*)(ws + 155189248);      // 524288
  unsigned short* wtl   = (unsigned short*)(ws + 155713536);      // 524288
  unsigned short* wot   = (unsigned short*)(ws + 156237824);      // 524288
  float*          keyn  = (float*)(ws + 156762112);               // 65536
  float*          mrow  = (float*)(ws + 156827648);               // 131072
  float*          rrow  = (float*)(ws + 156958720);               // 131072
  float*          uvec  = (float*)(ws + 157089792);               // 1024
  float*          vvec  = (float*)(ws + 157090816);               // 1024
  float*          d0    = (float*)(ws + 157091840);               // 256
  int*            top3  = (int*)(ws + 157092096);                 // 32768
  float*          wg2   = (float*)(ws + 157124864);               // 8192
  float*          dwv   = (float*)(ws + 157133056);               // 8192

  float* out   = (float*)d_out;
  float* outns = out + 33554432;

  k_prep<<<dim3(2113), dim3(256), 0, stream>>>(W_in, lnis, lnib, W_out, skeys, smem, wgate,
                                               wth, wtl, wot, keyn, d0, uvec, vvec);
  k_stats<<<dim3(4096), dim3(256), 0, stream>>>(x, mrow, rrow);
  k_gemm1<<<dim3(256), dim3(512), 0, stream>>>(x, wth, wtl, mrow, rrow, uvec, vvec, q_buf);
  k_attn<<<dim3(1024), dim3(512), 0, stream>>>(q_buf, smem, readb, summ);
  k_match<<<dim3(512), dim3(256), 0, stream>>>(summ, keyn, W_wr, wgate, top3, wv, wg2, dwv);
  k_scan<<<dim3(8), dim3(1024), 0, stream>>>(d0, top3, wg2, dwv, bgate, wv, smem, lnss, lnsb, outns);
  k_gemm2<<<dim3(1024), dim3(512), 0, stream>>>(readb, wot, out);
}

// Round 4
// 425.376 us; speedup vs baseline: 1.1572x; 1.0660x over previous
//
#include <hip/hip_runtime.h>

typedef __attribute__((ext_vector_type(8))) short s8v;
typedef __attribute__((ext_vector_type(4))) float f4v;

#define PAD1 88
#define KP 264
#define QP 260

__device__ __forceinline__ unsigned short f2bf(float f) {
  unsigned u = __float_as_uint(f);
  u += 0x7fffu + ((u >> 16) & 1u);
  return (unsigned short)(u >> 16);
}
__device__ __forceinline__ float bf2f(unsigned short h) {
  return __uint_as_float(((unsigned)h) << 16);
}
__device__ __forceinline__ float rdlanef(float v, int l) {
  return __uint_as_float(__builtin_amdgcn_readlane(__float_as_uint(v), l));
}

// ---------------- prep: W_in'=gamma*W_in split hi/lo transposed, W_out^T bf16,
//                  u=colsum(gamma*W_in), v=beta@W_in, key_norms, d0 ----------------
__global__ void k_prep(const float* __restrict__ W_in, const float* __restrict__ lnis,
                       const float* __restrict__ lnib, const float* __restrict__ W_out,
                       const float* __restrict__ skeys, const float* __restrict__ smem0,
                       const float* __restrict__ wgate,
                       unsigned short* __restrict__ wth, unsigned short* __restrict__ wtl,
                       unsigned short* __restrict__ wot, float* __restrict__ keyn,
                       float* __restrict__ d0, float* __restrict__ uvec, float* __restrict__ vvec)
{
  __shared__ float pr[4];
  const int bid = blockIdx.x, tid = threadIdx.x;
  if (bid < 1024) {
    int idx = bid * 256 + tid;           // wt layout [n=256][k=1024]
    int n = idx >> 10, k = idx & 1023;
    float val = lnis[k] * W_in[k * 256 + n];
    unsigned short h = f2bf(val);
    wth[idx] = h;
    wtl[idx] = f2bf(val - bf2f(h));
  } else if (bid < 2048) {
    int idx = (bid - 1024) * 256 + tid;  // wot layout [n=1024][k=256]
    int n = idx >> 8, k = idx & 255;
    wot[idx] = f2bf(W_out[k * 1024 + n]);
  } else if (bid == 2048) {
    float su = 0.f, sv = 0.f;
    for (int i = 0; i < 1024; ++i) {
      float wv_ = W_in[i * 256 + tid];
      su += lnis[i] * wv_;
      sv += lnib[i] * wv_;
    }
    uvec[tid] = su; vvec[tid] = sv;
  } else {
    int n = bid - 2049;
    float sk = skeys[n * 256 + tid];
    float sq = sk * sk;
    #pragma unroll
    for (int m = 32; m; m >>= 1) sq += __shfl_xor(sq, m);
    if ((tid & 63) == 0) pr[tid >> 6] = sq;
    __syncthreads();
    float tot = pr[0] + pr[1] + pr[2] + pr[3];
    keyn[n * 256 + tid] = sk * (1.0f / fmaxf(sqrtf(tot), 1e-12f));
    float pd = smem0[n * 256 + tid] * wgate[tid];
    #pragma unroll
    for (int m = 32; m; m >>= 1) pd += __shfl_xor(pd, m);
    __syncthreads();
    if ((tid & 63) == 0) pr[tid >> 6] = pd;
    __syncthreads();
    if (tid == 0) d0[n] = pr[0] + pr[1] + pr[2] + pr[3];
  }
}

// ---------------- per-row LN stats of x ----------------
__global__ void k_stats(const float* __restrict__ x, float* __restrict__ mrow, float* __restrict__ rrow)
{
  const int r = blockIdx.x * 8 + (threadIdx.x >> 5);
  const int j = threadIdx.x & 31;
  const float* p = x + (size_t)r * 1024 + j * 32;
  float s = 0.f, ss = 0.f;
  #pragma unroll
  for (int i = 0; i < 32; i += 4) {
    f4v v = *(const f4v*)(p + i);
    s  += v[0] + v[1] + v[2] + v[3];
    ss += v[0]*v[0] + v[1]*v[1] + v[2]*v[2] + v[3]*v[3];
  }
  #pragma unroll
  for (int m = 16; m; m >>= 1) { s += __shfl_xor(s, m); ss += __shfl_xor(ss, m); }
  if (j == 0) {
    float mean = s * (1.0f / 1024.0f);
    mrow[r] = mean;
    rrow[r] = rsqrtf(ss * (1.0f / 1024.0f) - mean * mean + 1e-5f);
  }
}

// ---------------- GEMM1: q = rstd*(x @ W') - rstd*m*u + v, split-bf16 (3 MFMA passes) ----------------
__global__ __launch_bounds__(512, 2) void k_gemm1(const float* __restrict__ x,
    const unsigned short* __restrict__ wth, const unsigned short* __restrict__ wtl,
    const float* __restrict__ mrow, const float* __restrict__ rrow,
    const float* __restrict__ uvec, const float* __restrict__ vvec,
    float* __restrict__ q)
{
  __shared__ unsigned short Ah[128 * PAD1], Al[128 * PAD1];
  __shared__ unsigned short Bh[256 * PAD1], Bl[256 * PAD1];
  __shared__ float uls[256], vls[256];
  const int tid = threadIdx.x;
  const int w = tid >> 6, lane = tid & 63;
  const int wm = w >> 2, wn = w & 3;
  const int row0 = blockIdx.x * 128;
  if (tid < 256) { uls[tid] = uvec[tid]; vls[tid] = vvec[tid]; }
  f4v zz = {0.f, 0.f, 0.f, 0.f};
  f4v acc[4][4];
  #pragma unroll
  for (int i = 0; i < 4; ++i)
    #pragma unroll
    for (int j = 0; j < 4; ++j) acc[i][j] = zz;
  const int rowA = tid >> 2, kqA = (tid & 3) * 16;
  const int colB = tid >> 1, khB = (tid & 1) * 32;
  for (int kt = 0; kt < 16; ++kt) {
    const int k0 = kt * 64;
    {
      const float* src = x + (size_t)(row0 + rowA) * 1024 + k0 + kqA;
      float vv[16];
      #pragma unroll
      for (int i = 0; i < 4; ++i) *(f4v*)(vv + 4 * i) = *(const f4v*)(src + 4 * i);
      unsigned short hh[16], ll[16];
      #pragma unroll
      for (int i = 0; i < 16; ++i) {
        unsigned short hsh = f2bf(vv[i]);
        hh[i] = hsh;
        ll[i] = f2bf(vv[i] - bf2f(hsh));
      }
      unsigned short* dh = &Ah[rowA * PAD1 + kqA];
      unsigned short* dl = &Al[rowA * PAD1 + kqA];
      *(s8v*)dh = *(const s8v*)hh; *(s8v*)(dh + 8) = *(const s8v*)(hh + 8);
      *(s8v*)dl = *(const s8v*)ll; *(s8v*)(dl + 8) = *(const s8v*)(ll + 8);
      const unsigned short* sh = wth + (size_t)colB * 1024 + k0 + khB;
      const unsigned short* sl = wtl + (size_t)colB * 1024 + k0 + khB;
      unsigned short* dbh = &Bh[colB * PAD1 + khB];
      unsigned short* dbl = &Bl[colB * PAD1 + khB];
      #pragma unroll
      for (int i = 0; i < 4; ++i) {
        *(s8v*)(dbh + 8 * i) = *(const s8v*)(sh + 8 * i);
        *(s8v*)(dbl + 8 * i) = *(const s8v*)(sl + 8 * i);
      }
    }
    __syncthreads();
    #pragma unroll
    for (int kk = 0; kk < 64; kk += 32) {
      const int kb = kk + (lane >> 4) * 8;
      s8v ah[4], al[4], bh[4], bl[4];
      #pragma unroll
      for (int mi = 0; mi < 4; ++mi) {
        const int rr = (wm * 64 + mi * 16 + (lane & 15)) * PAD1 + kb;
        ah[mi] = *(const s8v*)&Ah[rr];
        al[mi] = *(const s8v*)&Al[rr];
      }
      #pragma unroll
      for (int ni = 0; ni < 4; ++ni) {
        const int ccv = (wn * 64 + ni * 16 + (lane & 15)) * PAD1 + kb;
        bh[ni] = *(const s8v*)&Bh[ccv];
        bl[ni] = *(const s8v*)&Bl[ccv];
      }
      #pragma unroll
      for (int mi = 0; mi < 4; ++mi)
        #pragma unroll
        for (int ni = 0; ni < 4; ++ni) {
          acc[mi][ni] = __builtin_amdgcn_mfma_f32_16x16x32_bf16(ah[mi], bh[ni], acc[mi][ni], 0, 0, 0);
          acc[mi][ni] = __builtin_amdgcn_mfma_f32_16x16x32_bf16(ah[mi], bl[ni], acc[mi][ni], 0, 0, 0);
          acc[mi][ni] = __builtin_amdgcn_mfma_f32_16x16x32_bf16(al[mi], bh[ni], acc[mi][ni], 0, 0, 0);
        }
    }
    __syncthreads();
  }
  #pragma unroll
  for (int mi = 0; mi < 4; ++mi)
    #pragma unroll
    for (int j = 0; j < 4; ++j) {
      const int r = row0 + wm * 64 + mi * 16 + (lane >> 4) * 4 + j;
      const float mv = mrow[r], rv = rrow[r];
      #pragma unroll
      for (int ni = 0; ni < 4; ++ni) {
        const int cidx = wn * 64 + ni * 16 + (lane & 15);
        q[(size_t)r * 256 + cidx] = rv * acc[mi][ni][j] - rv * mv * uls[cidx] + vls[cidx];
      }
    }
}

// ---------------- attention: per wave = (chunk, head). softmax over 64 slots, read (bf16) + chunk summary ----------------
__global__ __launch_bounds__(512, 2) void k_attn(const float* __restrict__ q,
    const float* __restrict__ smem0, unsigned short* __restrict__ readb,
    float* __restrict__ summ)
{
  __shared__ float ks[64 * KP];
  __shared__ float qs[2][16 * QP];
  __shared__ float as_[8][64 * 20];
  const int tid = threadIdx.x;
  const int w = tid >> 6, lane = tid & 63;
  const int cl = w >> 2, h = w & 3;
  const int g = blockIdx.x * 2 + cl;
  const int bb = g >> 8, cc = g & 255;
  const int rowbase = bb * 4096 + cc * 16;

  #pragma unroll
  for (int i = 0; i < 32; ++i) {
    int idx = i * 512 + tid;
    ks[(idx >> 8) * KP + (idx & 255)] = smem0[idx];
  }
  {
    const int c2 = tid >> 8;
    const int rr = (tid >> 4) & 15;
    const int dq = (tid & 15) * 16;
    const int g2 = blockIdx.x * 2 + c2;
    const float* src = q + (size_t)((g2 >> 8) * 4096 + (g2 & 255) * 16 + rr) * 256 + dq;
    float* dst = &qs[c2][rr * QP + dq];
    #pragma unroll
    for (int i = 0; i < 4; ++i) *(f4v*)(dst + 4 * i) = *(const f4v*)(src + 4 * i);
  }
  __syncthreads();

  float S[16];
  #pragma unroll
  for (int t = 0; t < 16; ++t) S[t] = 0.f;
  const float* qsl = qs[cl];
  const int hb = h * 64;
  for (int c4 = 0; c4 < 16; ++c4) {
    f4v kv = *(const f4v*)&ks[lane * KP + hb + c4 * 4];
    #pragma unroll
    for (int t = 0; t < 16; ++t) {
      f4v qv = *(const f4v*)&qsl[t * QP + hb + c4 * 4];
      S[t] += qv[0] * kv[0] + qv[1] * kv[1] + qv[2] * kv[2] + qv[3] * kv[3];
    }
  }
  float rsum[16];
  #pragma unroll
  for (int t = 0; t < 16; ++t) {
    float sc = S[t] * 0.125f;
    float mx = sc;
    #pragma unroll
    for (int m = 32; m; m >>= 1) mx = fmaxf(mx, __shfl_xor(mx, m));
    float p = __expf(sc - mx);
    float sm = p;
    #pragma unroll
    for (int m = 32; m; m >>= 1) sm += __shfl_xor(sm, m);
    as_[w][lane * 20 + t] = p;
    rsum[t] = 1.0f / sm;
  }
  float r[16];
  #pragma unroll
  for (int t = 0; t < 16; ++t) r[t] = 0.f;
  for (int n = 0; n < 64; ++n) {
    float kv = ks[n * KP + hb + lane];
    const float* ap = &as_[w][n * 20];
    #pragma unroll
    for (int t4 = 0; t4 < 4; ++t4) {
      f4v av = *(const f4v*)(ap + t4 * 4);
      r[t4 * 4 + 0] += av[0] * kv; r[t4 * 4 + 1] += av[1] * kv;
      r[t4 * 4 + 2] += av[2] * kv; r[t4 * 4 + 3] += av[3] * kv;
    }
  }
  float sp = 0.f;
  #pragma unroll
  for (int t = 0; t < 16; ++t) {
    float rv = r[t] * rsum[t];
    sp += rv;
    readb[(size_t)(rowbase + t) * 256 + hb + lane] = f2bf(rv);
  }
  summ[(size_t)g * 256 + hb + lane] = sp * (1.0f / 16.0f);
}

// ---------------- per-chunk: match -> top3, wv = summary@W_write, wg2 = wv.Wg2, dwv = wv.Wg1 ----------------
__global__ void k_match(const float* __restrict__ summ, const float* __restrict__ keyn,
                        const float* __restrict__ Wwr, const float* __restrict__ wgate,
                        int* __restrict__ top3, float* __restrict__ wv,
                        float* __restrict__ wg2, float* __restrict__ dwv)
{
  __shared__ float sm[4][256];
  __shared__ float nrm_inv[4];
  __shared__ float mtch[4][64];
  __shared__ float redA[4][4], redB[4][4];
  const int tid = threadIdx.x, lane = tid & 63, w = tid >> 6;
  const int gbase = blockIdx.x * 4;
  #pragma unroll
  for (int gi = 0; gi < 4; ++gi) sm[gi][tid] = summ[(size_t)(gbase + gi) * 256 + tid];
  __syncthreads();
  {
    float ss = 0.f;
    #pragma unroll
    for (int i = 0; i < 4; ++i) { float vv_ = sm[w][lane + i * 64]; ss += vv_ * vv_; }
    #pragma unroll
    for (int m = 32; m; m >>= 1) ss += __shfl_xor(ss, m);
    if (lane == 0) nrm_inv[w] = 1.0f / fmaxf(sqrtf(ss), 1e-12f);
  }
  __syncthreads();
  {
    const int n = tid >> 2, qq = tid & 3;
    float mac[4] = {0.f, 0.f, 0.f, 0.f};
    const float* kp = keyn + n * 256 + qq * 64;
    for (int d = 0; d < 64; ++d) {
      float kv = kp[d];
      int dd = qq * 64 + d;
      mac[0] += sm[0][dd] * kv; mac[1] += sm[1][dd] * kv;
      mac[2] += sm[2][dd] * kv; mac[3] += sm[3][dd] * kv;
    }
    #pragma unroll
    for (int gi = 0; gi < 4; ++gi) {
      float v2_ = mac[gi];
      v2_ += __shfl_xor(v2_, 1);
      v2_ += __shfl_xor(v2_, 2);
      if (qq == 0) mtch[gi][n] = v2_ * nrm_inv[gi];
    }
  }
  __syncthreads();
  {
    float vorig = mtch[w][lane];
    #pragma unroll
    for (int it = 0; it < 3; ++it) {
      float rv = vorig; int ri = lane;
      #pragma unroll
      for (int m = 32; m; m >>= 1) {
        float ov = __shfl_xor(rv, m); int oi = __shfl_xor(ri, m);
        if (ov > rv || (ov == rv && oi < ri)) { rv = ov; ri = oi; }
      }
      if (lane == 0) top3[(gbase + w) * 4 + it] = ri;
      if (lane == ri) vorig = -3.0e38f;
    }
  }
  float wva[4] = {0.f, 0.f, 0.f, 0.f};
  for (int d = 0; d < 256; ++d) {
    float ww = Wwr[(size_t)d * 256 + tid];
    wva[0] += sm[0][d] * ww; wva[1] += sm[1][d] * ww;
    wva[2] += sm[2][d] * ww; wva[3] += sm[3][d] * ww;
  }
  const float g1 = wgate[tid], g2 = wgate[256 + tid];
  #pragma unroll
  for (int gi = 0; gi < 4; ++gi) {
    wv[(size_t)(gbase + gi) * 256 + tid] = wva[gi];
    float p2 = wva[gi] * g2, p1 = wva[gi] * g1;
    #pragma unroll
    for (int m = 32; m; m >>= 1) { p2 += __shfl_xor(p2, m); p1 += __shfl_xor(p1, m); }
    if (lane == 0) { redA[gi][w] = p2; redB[gi][w] = p1; }
  }
  __syncthreads();
  if (tid < 4) {
    wg2[gbase + tid] = redA[tid][0] + redA[tid][1] + redA[tid][2] + redA[tid][3];
    dwv[gbase + tid] = redB[tid][0] + redB[tid][1] + redB[tid][2] + redB[tid][3];
  }
}

// ---------------- scan: register gate chain -> closed-form coefficients W[n][c] ->
//                  load-parallel weighted sum over LDS-staged wv tiles -> LN ----------------
__global__ __launch_bounds__(1024) void k_scan(const float* __restrict__ d0,
    const int* __restrict__ top3, const float* __restrict__ wg2, const float* __restrict__ dwv,
    const float* __restrict__ bgate, const float* __restrict__ wv,
    const float* __restrict__ smem0, const float* __restrict__ lnss,
    const float* __restrict__ lnsb, float* __restrict__ outns)
{
  __shared__ float gls[256];
  __shared__ float Wl[256][64];   // Wl[c][n]: coefficient of wv[c] in slot n
  __shared__ float pn[64];        // product of (1-g) over all hits of slot n
  __shared__ float wvs[32][256];  // staged wv tile
  const int bb = blockIdx.x, tid = threadIdx.x;

  if (tid < 64) {
    const int lane = tid;
    const float bg = bgate[0];
    float dn = d0[lane];
    unsigned long long mk[4];
    // ---- forward gate chain (serial, register-resident) ----
    #pragma unroll
    for (int j = 0; j < 4; ++j) {
      const int c0 = j * 64;
      const int4 t3 = *(const int4*)&top3[(bb * 256 + c0 + lane) * 4];
      const int ixj = t3.x, iyj = t3.y, izj = t3.z;
      const float wzj = wg2[bb * 256 + c0 + lane] + bg;
      const float dvj = dwv[bb * 256 + c0 + lane];
      unsigned long long mkj = 0ull;
      float gout = 0.f;
      #pragma unroll 1
      for (int sl = 0; sl < 64; ++sl) {
        const int i0 = __builtin_amdgcn_readlane(ixj, sl);
        const int i1 = __builtin_amdgcn_readlane(iyj, sl);
        const int i2 = __builtin_amdgcn_readlane(izj, sl);
        const float wz = rdlanef(wzj, sl);
        const float dv = rdlanef(dvj, sl);
        const float s3 = rdlanef(dn, i0) + rdlanef(dn, i1) + rdlanef(dn, i2);
        const float z = s3 * (1.0f / 3.0f) + wz;
        const float gv = 1.0f / (1.0f + __expf(-z));
        if (lane == sl) gout = gv;
        const bool hit = (lane == i0) | (lane == i1) | (lane == i2);
        mkj |= ((unsigned long long)hit) << sl;
        dn = hit ? (1.0f - gv) * dn + gv * dv : dn;
      }
      gls[c0 + lane] = gout;
      mk[j] = mkj;
    }
    // ---- backward suffix-product pass: W[n][c] = hit * g_c * prod_{c'>c}(1-g_c') ----
    float running = 1.0f;
    #pragma unroll
    for (int j = 3; j >= 0; --j) {
      const unsigned long long mkj = mk[j];
      #pragma unroll 1
      for (int sl = 63; sl >= 0; --sl) {
        const int c = j * 64 + sl;
        const bool hit = (mkj >> sl) & 1ull;
        const float gv = gls[c];
        Wl[c][lane] = hit ? gv * running : 0.f;
        running = hit ? running * (1.0f - gv) : running;
      }
    }
    pn[lane] = running;
  }
  __syncthreads();

  // ---- load-parallel weighted accumulation ----
  const int n = tid >> 4, dq = tid & 15;
  float acc[16];
  {
    const float p = pn[n];
    const float* v0p = smem0 + n * 256 + dq * 16;
    #pragma unroll
    for (int i = 0; i < 16; i += 4) {
      f4v v0 = *(const f4v*)(v0p + i);
      acc[i] = p * v0[0]; acc[i + 1] = p * v0[1];
      acc[i + 2] = p * v0[2]; acc[i + 3] = p * v0[3];
    }
  }
  const int rr = tid >> 5, cc8 = (tid & 31) * 8;
  for (int ct = 0; ct < 8; ++ct) {
    __syncthreads();
    {
      const float* src = wv + (size_t)(bb * 256 + ct * 32 + rr) * 256 + cc8;
      *(f4v*)&wvs[rr][cc8] = *(const f4v*)src;
      *(f4v*)&wvs[rr][cc8 + 4] = *(const f4v*)(src + 4);
    }
    __syncthreads();
    #pragma unroll 1
    for (int cc = 0; cc < 32; ++cc) {
      const float coef = Wl[ct * 32 + cc][n];   // uniform within 16-thread group
      if (coef != 0.f) {
        const float* wp = &wvs[cc][dq * 16];
        #pragma unroll
        for (int i4 = 0; i4 < 4; ++i4) {
          f4v wq = *(const f4v*)(wp + i4 * 4);
          acc[i4 * 4 + 0] += coef * wq[0];
          acc[i4 * 4 + 1] += coef * wq[1];
          acc[i4 * 4 + 2] += coef * wq[2];
          acc[i4 * 4 + 3] += coef * wq[3];
        }
      }
    }
  }

  // ---- LayerNorm over each slot row (16-thread group) ----
  float s1 = 0.f;
  #pragma unroll
  for (int i = 0; i < 16; ++i) s1 += acc[i];
  #pragma unroll
  for (int m = 1; m < 16; m <<= 1) s1 += __shfl_xor(s1, m);
  const float mean = s1 * (1.0f / 256.0f);
  float s2 = 0.f;
  #pragma unroll
  for (int i = 0; i < 16; ++i) { float dd = acc[i] - mean; s2 += dd * dd; }
  #pragma unroll
  for (int m = 1; m < 16; m <<= 1) s2 += __shfl_xor(s2, m);
  const float rstd = rsqrtf(s2 * (1.0f / 256.0f) + 1e-5f);
  {
    const int base = (bb * 64 + n) * 256 + dq * 16;
    #pragma unroll
    for (int i = 0; i < 16; ++i) {
      int dd = dq * 16 + i;
      outns[base + i] = (acc[i] - mean) * rstd * lnss[dd] + lnsb[dd];
    }
  }
}

// ---------------- GEMM2: out = read(bf16) @ W_out (bf16 MFMA) ----------------
__global__ __launch_bounds__(512, 2) void k_gemm2(const unsigned short* __restrict__ a,
    const unsigned short* __restrict__ wot, float* __restrict__ out)
{
  __shared__ unsigned short As[128 * PAD1];
  __shared__ unsigned short Bs[256 * PAD1];
  const int tid = threadIdx.x;
  const int w = tid >> 6, lane = tid & 63;
  const int wm = w >> 2, wn = w & 3;
  const int mblk = blockIdx.x >> 2, nblk = blockIdx.x & 3;
  const int row0 = mblk * 128, n0 = nblk * 256;
  f4v zz = {0.f, 0.f, 0.f, 0.f};
  f4v acc[4][4];
  #pragma unroll
  for (int i = 0; i < 4; ++i)
    #pragma unroll
    for (int j = 0; j < 4; ++j) acc[i][j] = zz;
  const int rowA = tid >> 2, kqA = (tid & 3) * 16;
  const int colB = tid >> 1, khB = (tid & 1) * 32;
  for (int kt = 0; kt < 4; ++kt) {
    const int k0 = kt * 64;
    {
      const unsigned short* src = a + (size_t)(row0 + rowA) * 256 + k0 + kqA;
      *(s8v*)&As[rowA * PAD1 + kqA] = *(const s8v*)src;
      *(s8v*)&As[rowA * PAD1 + kqA + 8] = *(const s8v*)(src + 8);
      const unsigned short* sb = wot + (size_t)(n0 + colB) * 256 + k0 + khB;
      unsigned short* db = &Bs[colB * PAD1 + khB];
      #pragma unroll
      for (int i = 0; i < 4; ++i) *(s8v*)(db + 8 * i) = *(const s8v*)(sb + 8 * i);
    }
    __syncthreads();
    #pragma unroll
    for (int kk = 0; kk < 64; kk += 32) {
      const int kb = kk + (lane >> 4) * 8;
      s8v af[4], bf[4];
      #pragma unroll
      for (int mi = 0; mi < 4; ++mi)
        af[mi] = *(const s8v*)&As[(wm * 64 + mi * 16 + (lane & 15)) * PAD1 + kb];
      #pragma unroll
      for (int ni = 0; ni < 4; ++ni)
        bf[ni] = *(const s8v*)&Bs[(wn * 64 + ni * 16 + (lane & 15)) * PAD1 + kb];
      #pragma unroll
      for (int mi = 0; mi < 4; ++mi)
        #pragma unroll
        for (int ni = 0; ni < 4; ++ni)
          acc[mi][ni] = __builtin_amdgcn_mfma_f32_16x16x32_bf16(af[mi], bf[ni], acc[mi][ni], 0, 0, 0);
    }
    __syncthreads();
  }
  #pragma unroll
  for (int mi = 0; mi < 4; ++mi)
    #pragma unroll
    for (int j = 0; j < 4; ++j) {
      const int r = row0 + wm * 64 + mi * 16 + (lane >> 4) * 4 + j;
      #pragma unroll
      for (int ni = 0; ni < 4; ++ni) {
        const int cidx = wn * 64 + ni * 16 + (lane & 15);
        out[(size_t)r * 1024 + n0 + cidx] = acc[mi][ni][j];
      }
    }
}

extern "C" void kernel_launch(void* const* d_in, const int* in_sizes, int n_in,
                              void* d_out, int out_size, void* d_ws, size_t ws_size,
                              hipStream_t stream) {
  const float* x      = (const float*)d_in[0];
  const float* smem   = (const float*)d_in[1];
  const float* skeys  = (const float*)d_in[2];
  const float* W_in   = (const float*)d_in[3];
  const float* W_wr   = (const float*)d_in[4];
  const float* wgate  = (const float*)d_in[5];
  const float* bgate  = (const float*)d_in[6];
  const float* W_out  = (const float*)d_in[7];
  const float* lnis   = (const float*)d_in[8];
  const float* lnib   = (const float*)d_in[9];
  const float* lnss   = (const float*)d_in[10];
  const float* lnsb   = (const float*)d_in[11];
  (void)in_sizes; (void)n_in; (void)out_size; (void)ws_size;

  char* ws = (char*)d_ws;
  float*          q_buf = (float*)(ws + 0);                       // 134217728
  unsigned short* readb = (unsigned short*)(ws + 134217728);      // 16777216
  float*          summ  = (float*)(ws + 150994944);               // 2097152
  float*          wv    = (float*)(ws + 153092096);               // 2097152
  unsigned short* wth   = (unsigned short*)(ws + 155189248);      // 524288
  unsigned short* wtl   = (unsigned short*)(ws + 155713536);      // 524288
  unsigned short* wot   = (unsigned short*)(ws + 156237824);      // 524288
  float*          keyn  = (float*)(ws + 156762112);               // 65536
  float*          mrow  = (float*)(ws + 156827648);               // 131072
  float*          rrow  = (float*)(ws + 156958720);               // 131072
  float*          uvec  = (float*)(ws + 157089792);               // 1024
  float*          vvec  = (float*)(ws + 157090816);               // 1024
  float*          d0    = (float*)(ws + 157091840);               // 256
  int*            top3  = (int*)(ws + 157092096);                 // 32768
  float*          wg2   = (float*)(ws + 157124864);               // 8192
  float*          dwv   = (float*)(ws + 157133056);               // 8192

  float* out   = (float*)d_out;
  float* outns = out + 33554432;

  k_prep<<<dim3(2113), dim3(256), 0, stream>>>(W_in, lnis, lnib, W_out, skeys, smem, wgate,
                                               wth, wtl, wot, keyn, d0, uvec, vvec);
  k_stats<<<dim3(4096), dim3(256), 0, stream>>>(x, mrow, rrow);
  k_gemm1<<<dim3(256), dim3(512), 0, stream>>>(x, wth, wtl, mrow, rrow, uvec, vvec, q_buf);
  k_attn<<<dim3(1024), dim3(512), 0, stream>>>(q_buf, smem, readb, summ);
  k_match<<<dim3(512), dim3(256), 0, stream>>>(summ, keyn, W_wr, wgate, top3, wv, wg2, dwv);
  k_scan<<<dim3(8), dim3(1024), 0, stream>>>(d0, top3, wg2, dwv, bgate, wv, smem, lnss, lnsb, outns);
  k_gemm2<<<dim3(1024), dim3(512), 0, stream>>>(readb, wot, out);
}

// Round 5
// 364.166 us; speedup vs baseline: 1.3517x; 1.1681x over previous
//
#include <hip/hip_runtime.h>

typedef __attribute__((ext_vector_type(8))) short s8v;
typedef __attribute__((ext_vector_type(4))) float f4v;

#define PAD1 88

__device__ __forceinline__ unsigned short f2bf(float f) {
  unsigned u = __float_as_uint(f);
  u += 0x7fffu + ((u >> 16) & 1u);
  return (unsigned short)(u >> 16);
}
__device__ __forceinline__ float bf2f(unsigned short h) {
  return __uint_as_float(((unsigned)h) << 16);
}
__device__ __forceinline__ float rdlanef(float v, int l) {
  return __uint_as_float(__builtin_amdgcn_readlane(__float_as_uint(v), l));
}
__device__ __forceinline__ f4v vmax4(f4v a, f4v b) {
  f4v r; r[0]=fmaxf(a[0],b[0]); r[1]=fmaxf(a[1],b[1]); r[2]=fmaxf(a[2],b[2]); r[3]=fmaxf(a[3],b[3]); return r;
}
__device__ __forceinline__ f4v shflxor4(f4v v, int m) {
  f4v r; r[0]=__shfl_xor(v[0],m); r[1]=__shfl_xor(v[1],m); r[2]=__shfl_xor(v[2],m); r[3]=__shfl_xor(v[3],m); return r;
}
__device__ __forceinline__ f4v exp4(f4v v) {
  f4v r; r[0]=__expf(v[0]); r[1]=__expf(v[1]); r[2]=__expf(v[2]); r[3]=__expf(v[3]); return r;
}

// ---------------- prep ----------------
__global__ void k_prep(const float* __restrict__ W_in, const float* __restrict__ lnis,
                       const float* __restrict__ lnib, const float* __restrict__ W_out,
                       const float* __restrict__ skeys, const float* __restrict__ smem0,
                       const float* __restrict__ wgate,
                       unsigned short* __restrict__ wth, unsigned short* __restrict__ wtl,
                       unsigned short* __restrict__ wot, float* __restrict__ keyn,
                       float* __restrict__ d0, float* __restrict__ uvec, float* __restrict__ vvec)
{
  __shared__ float pr[4];
  const int bid = blockIdx.x, tid = threadIdx.x;
  if (bid < 1024) {
    int idx = bid * 256 + tid;           // wt layout [n=256][k=1024]
    int n = idx >> 10, k = idx & 1023;
    float val = lnis[k] * W_in[k * 256 + n];
    unsigned short h = f2bf(val);
    wth[idx] = h;
    wtl[idx] = f2bf(val - bf2f(h));
  } else if (bid < 2048) {
    int idx = (bid - 1024) * 256 + tid;  // wot layout [n=1024][k=256]
    int n = idx >> 8, k = idx & 255;
    wot[idx] = f2bf(W_out[k * 1024 + n]);
  } else if (bid == 2048) {
    float su = 0.f, sv = 0.f;
    for (int i = 0; i < 1024; ++i) {
      float wv_ = W_in[i * 256 + tid];
      su += lnis[i] * wv_;
      sv += lnib[i] * wv_;
    }
    uvec[tid] = su; vvec[tid] = sv;
  } else {
    int n = bid - 2049;
    float sk = skeys[n * 256 + tid];
    float sq = sk * sk;
    #pragma unroll
    for (int m = 32; m; m >>= 1) sq += __shfl_xor(sq, m);
    if ((tid & 63) == 0) pr[tid >> 6] = sq;
    __syncthreads();
    float tot = pr[0] + pr[1] + pr[2] + pr[3];
    keyn[n * 256 + tid] = sk * (1.0f / fmaxf(sqrtf(tot), 1e-12f));
    float pd = smem0[n * 256 + tid] * wgate[tid];
    #pragma unroll
    for (int m = 32; m; m >>= 1) pd += __shfl_xor(pd, m);
    __syncthreads();
    if ((tid & 63) == 0) pr[tid >> 6] = pd;
    __syncthreads();
    if (tid == 0) d0[n] = pr[0] + pr[1] + pr[2] + pr[3];
  }
}

// ---------------- per-row LN stats of x ----------------
__global__ void k_stats(const float* __restrict__ x, float* __restrict__ mrow, float* __restrict__ rrow)
{
  const int r = blockIdx.x * 8 + (threadIdx.x >> 5);
  const int j = threadIdx.x & 31;
  const float* p = x + (size_t)r * 1024 + j * 32;
  float s = 0.f, ss = 0.f;
  #pragma unroll
  for (int i = 0; i < 32; i += 4) {
    f4v v = *(const f4v*)(p + i);
    s  += v[0] + v[1] + v[2] + v[3];
    ss += v[0]*v[0] + v[1]*v[1] + v[2]*v[2] + v[3]*v[3];
  }
  #pragma unroll
  for (int m = 16; m; m >>= 1) { s += __shfl_xor(s, m); ss += __shfl_xor(ss, m); }
  if (j == 0) {
    float mean = s * (1.0f / 1024.0f);
    mrow[r] = mean;
    rrow[r] = rsqrtf(ss * (1.0f / 1024.0f) - mean * mean + 1e-5f);
  }
}

// ---------------- GEMM1: q = rstd*(x @ W') - rstd*m*u + v, split-bf16 (3 MFMA passes) ----------------
__global__ __launch_bounds__(512, 2) void k_gemm1(const float* __restrict__ x,
    const unsigned short* __restrict__ wth, const unsigned short* __restrict__ wtl,
    const float* __restrict__ mrow, const float* __restrict__ rrow,
    const float* __restrict__ uvec, const float* __restrict__ vvec,
    float* __restrict__ q)
{
  __shared__ unsigned short Ah[128 * PAD1], Al[128 * PAD1];
  __shared__ unsigned short Bh[256 * PAD1], Bl[256 * PAD1];
  __shared__ float uls[256], vls[256];
  const int tid = threadIdx.x;
  const int w = tid >> 6, lane = tid & 63;
  const int wm = w >> 2, wn = w & 3;
  const int row0 = blockIdx.x * 128;
  if (tid < 256) { uls[tid] = uvec[tid]; vls[tid] = vvec[tid]; }
  f4v zz = {0.f, 0.f, 0.f, 0.f};
  f4v acc[4][4];
  #pragma unroll
  for (int i = 0; i < 4; ++i)
    #pragma unroll
    for (int j = 0; j < 4; ++j) acc[i][j] = zz;
  const int rowA = tid >> 2, kqA = (tid & 3) * 16;
  const int colB = tid >> 1, khB = (tid & 1) * 32;
  for (int kt = 0; kt < 16; ++kt) {
    const int k0 = kt * 64;
    {
      const float* src = x + (size_t)(row0 + rowA) * 1024 + k0 + kqA;
      float vv[16];
      #pragma unroll
      for (int i = 0; i < 4; ++i) *(f4v*)(vv + 4 * i) = *(const f4v*)(src + 4 * i);
      unsigned short hh[16], ll[16];
      #pragma unroll
      for (int i = 0; i < 16; ++i) {
        unsigned short hsh = f2bf(vv[i]);
        hh[i] = hsh;
        ll[i] = f2bf(vv[i] - bf2f(hsh));
      }
      unsigned short* dh = &Ah[rowA * PAD1 + kqA];
      unsigned short* dl = &Al[rowA * PAD1 + kqA];
      *(s8v*)dh = *(const s8v*)hh; *(s8v*)(dh + 8) = *(const s8v*)(hh + 8);
      *(s8v*)dl = *(const s8v*)ll; *(s8v*)(dl + 8) = *(const s8v*)(ll + 8);
      const unsigned short* sh = wth + (size_t)colB * 1024 + k0 + khB;
      const unsigned short* sl = wtl + (size_t)colB * 1024 + k0 + khB;
      unsigned short* dbh = &Bh[colB * PAD1 + khB];
      unsigned short* dbl = &Bl[colB * PAD1 + khB];
      #pragma unroll
      for (int i = 0; i < 4; ++i) {
        *(s8v*)(dbh + 8 * i) = *(const s8v*)(sh + 8 * i);
        *(s8v*)(dbl + 8 * i) = *(const s8v*)(sl + 8 * i);
      }
    }
    __syncthreads();
    #pragma unroll
    for (int kk = 0; kk < 64; kk += 32) {
      const int kb = kk + (lane >> 4) * 8;
      s8v ah[4], al[4], bh[4], bl[4];
      #pragma unroll
      for (int mi = 0; mi < 4; ++mi) {
        const int rr = (wm * 64 + mi * 16 + (lane & 15)) * PAD1 + kb;
        ah[mi] = *(const s8v*)&Ah[rr];
        al[mi] = *(const s8v*)&Al[rr];
      }
      #pragma unroll
      for (int ni = 0; ni < 4; ++ni) {
        const int ccv = (wn * 64 + ni * 16 + (lane & 15)) * PAD1 + kb;
        bh[ni] = *(const s8v*)&Bh[ccv];
        bl[ni] = *(const s8v*)&Bl[ccv];
      }
      #pragma unroll
      for (int mi = 0; mi < 4; ++mi)
        #pragma unroll
        for (int ni = 0; ni < 4; ++ni) {
          acc[mi][ni] = __builtin_amdgcn_mfma_f32_16x16x32_bf16(ah[mi], bh[ni], acc[mi][ni], 0, 0, 0);
          acc[mi][ni] = __builtin_amdgcn_mfma_f32_16x16x32_bf16(ah[mi], bl[ni], acc[mi][ni], 0, 0, 0);
          acc[mi][ni] = __builtin_amdgcn_mfma_f32_16x16x32_bf16(al[mi], bh[ni], acc[mi][ni], 0, 0, 0);
        }
    }
    __syncthreads();
  }
  #pragma unroll
  for (int mi = 0; mi < 4; ++mi)
    #pragma unroll
    for (int j = 0; j < 4; ++j) {
      const int r = row0 + wm * 64 + mi * 16 + (lane >> 4) * 4 + j;
      const float mv = mrow[r], rv = rrow[r];
      #pragma unroll
      for (int ni = 0; ni < 4; ++ni) {
        const int cidx = wn * 64 + ni * 16 + (lane & 15);
        q[(size_t)r * 256 + cidx] = rv * acc[mi][ni][j] - rv * mv * uls[cidx] + vls[cidx];
      }
    }
}

// ---------------- attention via MFMA: scores split-bf16, softmax in regs,
//                  summary = colsum(P) @ Kf32 (exact), PV single bf16 ----------------
__global__ __launch_bounds__(512, 2) void k_attn(const float* __restrict__ q,
    const float* __restrict__ smem0, unsigned short* __restrict__ readb,
    float* __restrict__ summ)
{
  __shared__ float Kf[64 * 256];
  __shared__ float Pl[8][16 * 68];
  __shared__ float csm[8][64];
  const int tid = threadIdx.x;
  const int w = tid >> 6, lane = tid & 63;
  const int h = w & 3;
  const int l15 = lane & 15, kq = lane >> 4;

  // stage K as f32 (needed exact for the summary path)
  {
    const int base = tid * 32;
    #pragma unroll
    for (int i = 0; i < 8; ++i)
      *(f4v*)&Kf[base + i * 4] = *(const f4v*)&smem0[base + i * 4];
  }
  __syncthreads();

  // persistent B fragments (per wave, from LDS)
  s8v bsh[4][2], bsl[4][2], bpv[4][2];
  #pragma unroll
  for (int nt = 0; nt < 4; ++nt)
    #pragma unroll
    for (int ks = 0; ks < 2; ++ks) {
      const float* src = &Kf[(nt * 16 + l15) * 256 + h * 64 + ks * 32 + kq * 8];
      float tmp[8];
      *(f4v*)tmp = *(const f4v*)src; *(f4v*)(tmp + 4) = *(const f4v*)(src + 4);
      unsigned short hh[8], ll[8];
      #pragma unroll
      for (int j = 0; j < 8; ++j) {
        hh[j] = f2bf(tmp[j]);
        ll[j] = f2bf(tmp[j] - bf2f(hh[j]));
      }
      bsh[nt][ks] = *(const s8v*)hh;
      bsl[nt][ks] = *(const s8v*)ll;
      unsigned short pp[8];
      #pragma unroll
      for (int j = 0; j < 8; ++j)
        pp[j] = f2bf(Kf[(ks * 32 + kq * 8 + j) * 256 + h * 64 + nt * 16 + l15]);
      bpv[nt][ks] = *(const s8v*)pp;
    }

  const int g0 = blockIdx.x * 8 + (w >> 2) * 4;
  f4v qv[2][4];
  {
    #pragma unroll
    for (int ks = 0; ks < 2; ++ks) {
      const float* qp = q + (size_t)(g0 * 16 + l15) * 256 + h * 64 + ks * 32 + kq * 8;
      qv[0][ks * 2] = *(const f4v*)qp;
      qv[0][ks * 2 + 1] = *(const f4v*)(qp + 4);
    }
  }
  #pragma unroll
  for (int i = 0; i < 4; ++i) {
    const int cur = i & 1, nxt = cur ^ 1;
    if (i < 3) {
      const int gn = g0 + i + 1;
      #pragma unroll
      for (int ks = 0; ks < 2; ++ks) {
        const float* qp = q + (size_t)(gn * 16 + l15) * 256 + h * 64 + ks * 32 + kq * 8;
        qv[nxt][ks * 2] = *(const f4v*)qp;
        qv[nxt][ks * 2 + 1] = *(const f4v*)(qp + 4);
      }
    }
    const int g = g0 + i;
    // A fragments hi/lo
    s8v ah[2], al[2];
    #pragma unroll
    for (int ks = 0; ks < 2; ++ks) {
      float tmp[8];
      *(f4v*)tmp = qv[cur][ks * 2]; *(f4v*)(tmp + 4) = qv[cur][ks * 2 + 1];
      unsigned short hh[8], ll[8];
      #pragma unroll
      for (int j = 0; j < 8; ++j) {
        hh[j] = f2bf(tmp[j]);
        ll[j] = f2bf(tmp[j] - bf2f(hh[j]));
      }
      ah[ks] = *(const s8v*)hh; al[ks] = *(const s8v*)ll;
    }
    // scores: 3-pass split bf16
    f4v zz = {0.f, 0.f, 0.f, 0.f};
    f4v sacc[4] = {zz, zz, zz, zz};
    #pragma unroll
    for (int ks = 0; ks < 2; ++ks)
      #pragma unroll
      for (int nt = 0; nt < 4; ++nt) {
        sacc[nt] = __builtin_amdgcn_mfma_f32_16x16x32_bf16(ah[ks], bsh[nt][ks], sacc[nt], 0, 0, 0);
        sacc[nt] = __builtin_amdgcn_mfma_f32_16x16x32_bf16(ah[ks], bsl[nt][ks], sacc[nt], 0, 0, 0);
        sacc[nt] = __builtin_amdgcn_mfma_f32_16x16x32_bf16(al[ks], bsh[nt][ks], sacc[nt], 0, 0, 0);
      }
    // softmax over 64 slots per row (rows = kq*4+j, slots = nt*16 + l15)
    #pragma unroll
    for (int nt = 0; nt < 4; ++nt) sacc[nt] = sacc[nt] * 0.125f;
    f4v mx = vmax4(vmax4(sacc[0], sacc[1]), vmax4(sacc[2], sacc[3]));
    #pragma unroll
    for (int m = 1; m <= 8; m <<= 1) mx = vmax4(mx, shflxor4(mx, m));
    f4v p[4];
    f4v psum = zz;
    #pragma unroll
    for (int nt = 0; nt < 4; ++nt) { p[nt] = exp4(sacc[nt] - mx); psum = psum + p[nt]; }
    #pragma unroll
    for (int m = 1; m <= 8; m <<= 1) psum = psum + shflxor4(psum, m);
    f4v rs;
    rs[0] = 1.0f / psum[0]; rs[1] = 1.0f / psum[1];
    rs[2] = 1.0f / psum[2]; rs[3] = 1.0f / psum[3];
    #pragma unroll
    for (int nt = 0; nt < 4; ++nt) p[nt] = p[nt] * rs;
    // colsum for exact summary
    float cs4[4];
    #pragma unroll
    for (int nt = 0; nt < 4; ++nt) {
      cs4[nt] = p[nt][0] + p[nt][1] + p[nt][2] + p[nt][3];
      cs4[nt] += __shfl_xor(cs4[nt], 16);
      cs4[nt] += __shfl_xor(cs4[nt], 32);
    }
    if (kq == 0) {
      #pragma unroll
      for (int nt = 0; nt < 4; ++nt) csm[w][nt * 16 + l15] = cs4[nt];
    }
    // stage P (f32) for transpose into A-fragments
    #pragma unroll
    for (int nt = 0; nt < 4; ++nt)
      #pragma unroll
      for (int j = 0; j < 4; ++j)
        Pl[w][(kq * 4 + j) * 68 + nt * 16 + l15] = p[nt][j];
    // P A-fragments (single bf16 — readb is bf16 anyway)
    s8v pa[2];
    #pragma unroll
    for (int ks = 0; ks < 2; ++ks) {
      const float* pp = &Pl[w][l15 * 68 + ks * 32 + kq * 8];
      float tmp[8];
      *(f4v*)tmp = *(const f4v*)pp; *(f4v*)(tmp + 4) = *(const f4v*)(pp + 4);
      unsigned short uu[8];
      #pragma unroll
      for (int j = 0; j < 8; ++j) uu[j] = f2bf(tmp[j]);
      pa[ks] = *(const s8v*)uu;
    }
    // PV
    f4v racc[4] = {zz, zz, zz, zz};
    #pragma unroll
    for (int ks = 0; ks < 2; ++ks)
      #pragma unroll
      for (int nt = 0; nt < 4; ++nt)
        racc[nt] = __builtin_amdgcn_mfma_f32_16x16x32_bf16(pa[ks], bpv[nt][ks], racc[nt], 0, 0, 0);
    // store read (bf16)
    const int rowbase = (g >> 8) * 4096 + (g & 255) * 16;
    #pragma unroll
    for (int nt = 0; nt < 4; ++nt)
      #pragma unroll
      for (int j = 0; j < 4; ++j)
        readb[(size_t)(rowbase + kq * 4 + j) * 256 + h * 64 + nt * 16 + l15] = f2bf(racc[nt][j]);
    // exact summary: (1/16) * colsum @ Kf32
    float s = 0.f;
    #pragma unroll 8
    for (int n = 0; n < 64; ++n) s += csm[w][n] * Kf[n * 256 + h * 64 + lane];
    summ[(size_t)g * 256 + h * 64 + lane] = s * (1.0f / 16.0f);
  }
}

// ---------------- per-chunk: match -> top3, wv = summary@W_write, wg2 = wv.Wg2, dwv = wv.Wg1 ----------------
__global__ void k_match(const float* __restrict__ summ, const float* __restrict__ keyn,
                        const float* __restrict__ Wwr, const float* __restrict__ wgate,
                        int* __restrict__ top3, float* __restrict__ wv,
                        float* __restrict__ wg2, float* __restrict__ dwv)
{
  __shared__ float sm[4][256];
  __shared__ float nrm_inv[4];
  __shared__ float mtch[4][64];
  __shared__ float redA[4][4], redB[4][4];
  const int tid = threadIdx.x, lane = tid & 63, w = tid >> 6;
  const int gbase = blockIdx.x * 4;
  #pragma unroll
  for (int gi = 0; gi < 4; ++gi) sm[gi][tid] = summ[(size_t)(gbase + gi) * 256 + tid];
  __syncthreads();
  {
    float ss = 0.f;
    #pragma unroll
    for (int i = 0; i < 4; ++i) { float vv_ = sm[w][lane + i * 64]; ss += vv_ * vv_; }
    #pragma unroll
    for (int m = 32; m; m >>= 1) ss += __shfl_xor(ss, m);
    if (lane == 0) nrm_inv[w] = 1.0f / fmaxf(sqrtf(ss), 1e-12f);
  }
  __syncthreads();
  {
    const int n = tid >> 2, qq = tid & 3;
    float mac[4] = {0.f, 0.f, 0.f, 0.f};
    const float* kp = keyn + n * 256 + qq * 64;
    for (int d = 0; d < 64; ++d) {
      float kv = kp[d];
      int dd = qq * 64 + d;
      mac[0] += sm[0][dd] * kv; mac[1] += sm[1][dd] * kv;
      mac[2] += sm[2][dd] * kv; mac[3] += sm[3][dd] * kv;
    }
    #pragma unroll
    for (int gi = 0; gi < 4; ++gi) {
      float v2_ = mac[gi];
      v2_ += __shfl_xor(v2_, 1);
      v2_ += __shfl_xor(v2_, 2);
      if (qq == 0) mtch[gi][n] = v2_ * nrm_inv[gi];
    }
  }
  __syncthreads();
  {
    float vorig = mtch[w][lane];
    #pragma unroll
    for (int it = 0; it < 3; ++it) {
      float rv = vorig; int ri = lane;
      #pragma unroll
      for (int m = 32; m; m >>= 1) {
        float ov = __shfl_xor(rv, m); int oi = __shfl_xor(ri, m);
        if (ov > rv || (ov == rv && oi < ri)) { rv = ov; ri = oi; }
      }
      if (lane == 0) top3[(gbase + w) * 4 + it] = ri;
      if (lane == ri) vorig = -3.0e38f;
    }
  }
  float wva[4] = {0.f, 0.f, 0.f, 0.f};
  for (int d = 0; d < 256; ++d) {
    float ww = Wwr[(size_t)d * 256 + tid];
    wva[0] += sm[0][d] * ww; wva[1] += sm[1][d] * ww;
    wva[2] += sm[2][d] * ww; wva[3] += sm[3][d] * ww;
  }
  const float g1 = wgate[tid], g2 = wgate[256 + tid];
  #pragma unroll
  for (int gi = 0; gi < 4; ++gi) {
    wv[(size_t)(gbase + gi) * 256 + tid] = wva[gi];
    float p2 = wva[gi] * g2, p1 = wva[gi] * g1;
    #pragma unroll
    for (int m = 32; m; m >>= 1) { p2 += __shfl_xor(p2, m); p1 += __shfl_xor(p1, m); }
    if (lane == 0) { redA[gi][w] = p2; redB[gi][w] = p1; }
  }
  __syncthreads();
  if (tid < 4) {
    wg2[gbase + tid] = redA[tid][0] + redA[tid][1] + redA[tid][2] + redA[tid][3];
    dwv[gbase + tid] = redB[tid][0] + redB[tid][1] + redB[tid][2] + redB[tid][3];
  }
}

// ---------------- scan: register gate chain -> closed-form coefficients W[n][c] ->
//                  load-parallel weighted sum over LDS-staged wv tiles -> LN ----------------
__global__ __launch_bounds__(1024) void k_scan(const float* __restrict__ d0,
    const int* __restrict__ top3, const float* __restrict__ wg2, const float* __restrict__ dwv,
    const float* __restrict__ bgate, const float* __restrict__ wv,
    const float* __restrict__ smem0, const float* __restrict__ lnss,
    const float* __restrict__ lnsb, float* __restrict__ outns)
{
  __shared__ float gls[256];
  __shared__ float Wl[256][64];   // Wl[c][n]: coefficient of wv[c] in slot n
  __shared__ float pn[64];        // product of (1-g) over all hits of slot n
  __shared__ float wvs[32][256];  // staged wv tile
  const int bb = blockIdx.x, tid = threadIdx.x;

  if (tid < 64) {
    const int lane = tid;
    const float bg = bgate[0];
    float dn = d0[lane];
    unsigned long long mk[4];
    // ---- forward gate chain (serial, register-resident) ----
    #pragma unroll
    for (int j = 0; j < 4; ++j) {
      const int c0 = j * 64;
      const int4 t3 = *(const int4*)&top3[(bb * 256 + c0 + lane) * 4];
      const int ixj = t3.x, iyj = t3.y, izj = t3.z;
      const float wzj = wg2[bb * 256 + c0 + lane] + bg;
      const float dvj = dwv[bb * 256 + c0 + lane];
      unsigned long long mkj = 0ull;
      float gout = 0.f;
      #pragma unroll 1
      for (int sl = 0; sl < 64; ++sl) {
        const int i0 = __builtin_amdgcn_readlane(ixj, sl);
        const int i1 = __builtin_amdgcn_readlane(iyj, sl);
        const int i2 = __builtin_amdgcn_readlane(izj, sl);
        const float wz = rdlanef(wzj, sl);
        const float dv = rdlanef(dvj, sl);
        const float s3 = rdlanef(dn, i0) + rdlanef(dn, i1) + rdlanef(dn, i2);
        const float z = s3 * (1.0f / 3.0f) + wz;
        const float gv = 1.0f / (1.0f + __expf(-z));
        if (lane == sl) gout = gv;
        const bool hit = (lane == i0) | (lane == i1) | (lane == i2);
        mkj |= ((unsigned long long)hit) << sl;
        dn = hit ? (1.0f - gv) * dn + gv * dv : dn;
      }
      gls[c0 + lane] = gout;
      mk[j] = mkj;
    }
    // ---- backward suffix-product pass: W[n][c] = hit * g_c * prod_{c'>c}(1-g_c') ----
    float running = 1.0f;
    #pragma unroll
    for (int j = 3; j >= 0; --j) {
      const unsigned long long mkj = mk[j];
      #pragma unroll 1
      for (int sl = 63; sl >= 0; --sl) {
        const int c = j * 64 + sl;
        const bool hit = (mkj >> sl) & 1ull;
        const float gv = gls[c];
        Wl[c][lane] = hit ? gv * running : 0.f;
        running = hit ? running * (1.0f - gv) : running;
      }
    }
    pn[lane] = running;
  }
  __syncthreads();

  // ---- load-parallel weighted accumulation ----
  const int n = tid >> 4, dq = tid & 15;
  float acc[16];
  {
    const float p = pn[n];
    const float* v0p = smem0 + n * 256 + dq * 16;
    #pragma unroll
    for (int i = 0; i < 16; i += 4) {
      f4v v0 = *(const f4v*)(v0p + i);
      acc[i] = p * v0[0]; acc[i + 1] = p * v0[1];
      acc[i + 2] = p * v0[2]; acc[i + 3] = p * v0[3];
    }
  }
  const int rr = tid >> 5, cc8 = (tid & 31) * 8;
  for (int ct = 0; ct < 8; ++ct) {
    __syncthreads();
    {
      const float* src = wv + (size_t)(bb * 256 + ct * 32 + rr) * 256 + cc8;
      *(f4v*)&wvs[rr][cc8] = *(const f4v*)src;
      *(f4v*)&wvs[rr][cc8 + 4] = *(const f4v*)(src + 4);
    }
    __syncthreads();
    #pragma unroll 1
    for (int cc = 0; cc < 32; ++cc) {
      const float coef = Wl[ct * 32 + cc][n];   // uniform within 16-thread group
      if (coef != 0.f) {
        const float* wp = &wvs[cc][dq * 16];
        #pragma unroll
        for (int i4 = 0; i4 < 4; ++i4) {
          f4v wq = *(const f4v*)(wp + i4 * 4);
          acc[i4 * 4 + 0] += coef * wq[0];
          acc[i4 * 4 + 1] += coef * wq[1];
          acc[i4 * 4 + 2] += coef * wq[2];
          acc[i4 * 4 + 3] += coef * wq[3];
        }
      }
    }
  }

  // ---- LayerNorm over each slot row (16-thread group) ----
  float s1 = 0.f;
  #pragma unroll
  for (int i = 0; i < 16; ++i) s1 += acc[i];
  #pragma unroll
  for (int m = 1; m < 16; m <<= 1) s1 += __shfl_xor(s1, m);
  const float mean = s1 * (1.0f / 256.0f);
  float s2 = 0.f;
  #pragma unroll
  for (int i = 0; i < 16; ++i) { float dd = acc[i] - mean; s2 += dd * dd; }
  #pragma unroll
  for (int m = 1; m < 16; m <<= 1) s2 += __shfl_xor(s2, m);
  const float rstd = rsqrtf(s2 * (1.0f / 256.0f) + 1e-5f);
  {
    const int base = (bb * 64 + n) * 256 + dq * 16;
    #pragma unroll
    for (int i = 0; i < 16; ++i) {
      int dd = dq * 16 + i;
      outns[base + i] = (acc[i] - mean) * rstd * lnss[dd] + lnsb[dd];
    }
  }
}

// ---------------- GEMM2: out = read(bf16) @ W_out (bf16 MFMA) ----------------
__global__ __launch_bounds__(512, 2) void k_gemm2(const unsigned short* __restrict__ a,
    const unsigned short* __restrict__ wot, float* __restrict__ out)
{
  __shared__ unsigned short As[128 * PAD1];
  __shared__ unsigned short Bs[256 * PAD1];
  const int tid = threadIdx.x;
  const int w = tid >> 6, lane = tid & 63;
  const int wm = w >> 2, wn = w & 3;
  const int mblk = blockIdx.x >> 2, nblk = blockIdx.x & 3;
  const int row0 = mblk * 128, n0 = nblk * 256;
  f4v zz = {0.f, 0.f, 0.f, 0.f};
  f4v acc[4][4];
  #pragma unroll
  for (int i = 0; i < 4; ++i)
    #pragma unroll
    for (int j = 0; j < 4; ++j) acc[i][j] = zz;
  const int rowA = tid >> 2, kqA = (tid & 3) * 16;
  const int colB = tid >> 1, khB = (tid & 1) * 32;
  for (int kt = 0; kt < 4; ++kt) {
    const int k0 = kt * 64;
    {
      const unsigned short* src = a + (size_t)(row0 + rowA) * 256 + k0 + kqA;
      *(s8v*)&As[rowA * PAD1 + kqA] = *(const s8v*)src;
      *(s8v*)&As[rowA * PAD1 + kqA + 8] = *(const s8v*)(src + 8);
      const unsigned short* sb = wot + (size_t)(n0 + colB) * 256 + k0 + khB;
      unsigned short* db = &Bs[colB * PAD1 + khB];
      #pragma unroll
      for (int i = 0; i < 4; ++i) *(s8v*)(db + 8 * i) = *(const s8v*)(sb + 8 * i);
    }
    __syncthreads();
    #pragma unroll
    for (int kk = 0; kk < 64; kk += 32) {
      const int kb = kk + (lane >> 4) * 8;
      s8v af[4], bf[4];
      #pragma unroll
      for (int mi = 0; mi < 4; ++mi)
        af[mi] = *(const s8v*)&As[(wm * 64 + mi * 16 + (lane & 15)) * PAD1 + kb];
      #pragma unroll
      for (int ni = 0; ni < 4; ++ni)
        bf[ni] = *(const s8v*)&Bs[(wn * 64 + ni * 16 + (lane & 15)) * PAD1 + kb];
      #pragma unroll
      for (int mi = 0; mi < 4; ++mi)
        #pragma unroll
        for (int ni = 0; ni < 4; ++ni)
          acc[mi][ni] = __builtin_amdgcn_mfma_f32_16x16x32_bf16(af[mi], bf[ni], acc[mi][ni], 0, 0, 0);
    }
    __syncthreads();
  }
  #pragma unroll
  for (int mi = 0; mi < 4; ++mi)
    #pragma unroll
    for (int j = 0; j < 4; ++j) {
      const int r = row0 + wm * 64 + mi * 16 + (lane >> 4) * 4 + j;
      #pragma unroll
      for (int ni = 0; ni < 4; ++ni) {
        const int cidx = wn * 64 + ni * 16 + (lane & 15);
        out[(size_t)r * 1024 + n0 + cidx] = acc[mi][ni][j];
      }
    }
}

extern "C" void kernel_launch(void* const* d_in, const int* in_sizes, int n_in,
                              void* d_out, int out_size, void* d_ws, size_t ws_size,
                              hipStream_t stream) {
  const float* x      = (const float*)d_in[0];
  const float* smem   = (const float*)d_in[1];
  const float* skeys  = (const float*)d_in[2];
  const float* W_in   = (const float*)d_in[3];
  const float* W_wr   = (const float*)d_in[4];
  const float* wgate  = (const float*)d_in[5];
  const float* bgate  = (const float*)d_in[6];
  const float* W_out  = (const float*)d_in[7];
  const float* lnis   = (const float*)d_in[8];
  const float* lnib   = (const float*)d_in[9];
  const float* lnss   = (const float*)d_in[10];
  const float* lnsb   = (const float*)d_in[11];
  (void)in_sizes; (void)n_in; (void)out_size; (void)ws_size;

  char* ws = (char*)d_ws;
  float*          q_buf = (float*)(ws + 0);                       // 134217728
  unsigned short* readb = (unsigned short*)(ws + 134217728);      // 16777216
  float*          summ  = (float*)(ws + 150994944);               // 2097152
  float*          wv    = (float*)(ws + 153092096);               // 2097152
  unsigned short* wth   = (unsigned short*)(ws + 155189248);      // 524288
  unsigned short* wtl   = (unsigned short*)(ws + 155713536);      // 524288
  unsigned short* wot   = (unsigned short*)(ws + 156237824);      // 524288
  float*          keyn  = (float*)(ws + 156762112);               // 65536
  float*          mrow  = (float*)(ws + 156827648);               // 131072
  float*          rrow  = (float*)(ws + 156958720);               // 131072
  float*          uvec  = (float*)(ws + 157089792);               // 1024
  float*          vvec  = (float*)(ws + 157090816);               // 1024
  float*          d0    = (float*)(ws + 157091840);               // 256
  int*            top3  = (int*)(ws + 157092096);                 // 32768
  float*          wg2   = (float*)(ws + 157124864);               // 8192
  float*          dwv   = (float*)(ws + 157133056);               // 8192

  float* out   = (float*)d_out;
  float* outns = out + 33554432;

  k_prep<<<dim3(2113), dim3(256), 0, stream>>>(W_in, lnis, lnib, W_out, skeys, smem, wgate,
                                               wth, wtl, wot, keyn, d0, uvec, vvec);
  k_stats<<<dim3(4096), dim3(256), 0, stream>>>(x, mrow, rrow);
  k_gemm1<<<dim3(256), dim3(512), 0, stream>>>(x, wth, wtl, mrow, rrow, uvec, vvec, q_buf);
  k_attn<<<dim3(256), dim3(512), 0, stream>>>(q_buf, smem, readb, summ);
  k_match<<<dim3(512), dim3(256), 0, stream>>>(summ, keyn, W_wr, wgate, top3, wv, wg2, dwv);
  k_scan<<<dim3(8), dim3(1024), 0, stream>>>(d0, top3, wg2, dwv, bgate, wv, smem, lnss, lnsb, outns);
  k_gemm2<<<dim3(1024), dim3(512), 0, stream>>>(readb, wot, out);
}